// Round 7
// baseline (168.914 us; speedup 1.0000x reference)
//
#include <hip/hip_runtime.h>

#define BB 8
#define CC 512
#define SS 1024   // H*W
#define EMB 512
#define HEADS 8
#define DH 64
#define GROUPS 32
#define CPG 16
#define EPS 1e-5f

typedef __bf16 bf16x8 __attribute__((ext_vector_type(8)));
typedef __bf16 bf16x4 __attribute__((ext_vector_type(4)));
typedef float f32x4 __attribute__((ext_vector_type(4)));
typedef unsigned short u16x4 __attribute__((ext_vector_type(4)));

__device__ inline unsigned short f2bf(float f) {
    union { float f; unsigned u; } c; c.f = f;
    unsigned u = c.u + 0x7FFF + ((c.u >> 16) & 1);   // RNE
    return (unsigned short)(u >> 16);
}

#if defined(__has_builtin)
#if __has_builtin(__builtin_amdgcn_exp2f)
#define EXP2F(x) __builtin_amdgcn_exp2f(x)
#endif
#endif
#ifndef EXP2F
#define EXP2F(x) __expf(0.69314718f * (x))
#endif

#define MFMA16(a, b, c) __builtin_amdgcn_mfma_f32_16x16x32_bf16((a), (b), (c), 0, 0, 0)
#define GLOAD_LDS16(g, s)                                                     \
    __builtin_amdgcn_global_load_lds(                                         \
        (const __attribute__((address_space(1))) void*)(g),                   \
        (__attribute__((address_space(3))) void*)(s), 16, 0, 0)

// ---------------------------------------------------------------------------
// Prep (fused): blocks 0..4095 transpose x -> xT bf16; 4096..5119 transpose
// the four weight matrices -> Wt bf16 (K-major).
// ---------------------------------------------------------------------------
__global__ __launch_bounds__(256) void prep_all(
    const float* __restrict__ x,
    const float* __restrict__ Wq, const float* __restrict__ Wk,
    const float* __restrict__ Wv, const float* __restrict__ Wo,
    unsigned short* __restrict__ xT, unsigned short* __restrict__ Wt)
{
    __shared__ float tile[32][33];
    const int t = threadIdx.x;

    if (blockIdx.x < 4096) {
        const int i  = blockIdx.x;
        const int s0 = (i & 31) * 32;
        const int c0 = ((i >> 5) & 15) * 32;
        const int b  = i >> 9;
        {
            int c = t >> 3, s4 = (t & 7) * 4;
            float4 v = *(const float4*)(x + ((size_t)b * CC + c0 + c) * SS + s0 + s4);
            tile[c][s4] = v.x; tile[c][s4 + 1] = v.y;
            tile[c][s4 + 2] = v.z; tile[c][s4 + 3] = v.w;
        }
        __syncthreads();
        {
            int sr = t >> 3, c4 = (t & 7) * 4;
            u16x4 o;
            #pragma unroll
            for (int i2 = 0; i2 < 4; ++i2) o[i2] = f2bf(tile[c4 + i2][sr]);
            *(u16x4*)(xT + ((size_t)(b << 10) + s0 + sr) * CC + c0 + c4) = o;
        }
    } else {
        const int i  = blockIdx.x - 4096;
        const int k0 = (i & 15) * 32;
        const int n0 = ((i >> 4) & 15) * 32;
        const int z  = i >> 8;
        const float* W = (z == 0) ? Wq : (z == 1) ? Wk : (z == 2) ? Wv : Wo;
        unsigned short* dst = Wt + (size_t)z * EMB * CC;
        {
            int k = t >> 3, n4 = (t & 7) * 4;
            float4 v = *(const float4*)(W + (size_t)(k0 + k) * EMB + n0 + n4);
            tile[k][n4] = v.x; tile[k][n4 + 1] = v.y;
            tile[k][n4 + 2] = v.z; tile[k][n4 + 3] = v.w;
        }
        __syncthreads();
        {
            int n = t >> 3, k4 = (t & 7) * 4;
            u16x4 o;
            #pragma unroll
            for (int i2 = 0; i2 < 4; ++i2) o[i2] = f2bf(tile[k4 + i2][n]);
            *(u16x4*)(dst + (size_t)(n0 + n) * CC + k0 + k4) = o;
        }
    }
}

// ---------------------------------------------------------------------------
// MFMA GEMM core: 128x128 tile, BK=32, 4 waves 2x2, dbuf LDS via
// global_load_lds(16B), slot-XOR swizzle (pre-swizzled source).
// ---------------------------------------------------------------------------
#define GEMM_CORE(Aptr, Bptr)                                                  \
    __shared__ __align__(16) char lds[32768];                                  \
    const int t = threadIdx.x, w = t >> 6, l = t & 63;                         \
    const int wr = w >> 1, wc = w & 1;                                         \
    const int rl = l & 15, kh = l >> 4;                                        \
    f32x4 acc[4][4] = {};                                                      \
    {                                                                          \
        const int srow = w * 32 + (l >> 2);                                    \
        const int sslot = (l & 3) ^ ((srow >> 1) & 3);                         \
        const char* Ag0 = (const char*)(Aptr) + (size_t)(m0 + srow) * 1024 + sslot * 16;      \
        const char* Ag1 = (const char*)(Aptr) + (size_t)(m0 + srow + 16) * 1024 + (((l & 3) ^ (((srow + 16) >> 1) & 3)) * 16); \
        const char* Bg0 = (const char*)(Bptr) + (size_t)(n0 + srow) * 1024 + sslot * 16;      \
        const char* Bg1 = (const char*)(Bptr) + (size_t)(n0 + srow + 16) * 1024 + (((l & 3) ^ (((srow + 16) >> 1) & 3)) * 16); \
        for (int kt = 0; kt < 16; ++kt) {                                      \
            if (kt == 0) {                                                     \
                GLOAD_LDS16(Ag0, lds + w * 2048);                              \
                GLOAD_LDS16(Ag1, lds + w * 2048 + 1024);                       \
                GLOAD_LDS16(Bg0, lds + 8192 + w * 2048);                       \
                GLOAD_LDS16(Bg1, lds + 8192 + w * 2048 + 1024);                \
                __syncthreads();                                               \
            }                                                                  \
            const int buf = kt & 1;                                            \
            if (kt < 15) {                                                     \
                const int kb = (kt + 1) * 64;                                  \
                char* Al = lds + (buf ^ 1) * 16384;                            \
                char* Bl = Al + 8192;                                          \
                GLOAD_LDS16(Ag0 + kb, Al + w * 2048);                          \
                GLOAD_LDS16(Ag1 + kb, Al + w * 2048 + 1024);                   \
                GLOAD_LDS16(Bg0 + kb, Bl + w * 2048);                          \
                GLOAD_LDS16(Bg1 + kb, Bl + w * 2048 + 1024);                   \
            }                                                                  \
            const char* Al = lds + buf * 16384;                                \
            const char* Bl = Al + 8192;                                        \
            bf16x8 af[4], bfr[4];                                              \
            _Pragma("unroll")                                                  \
            for (int i = 0; i < 4; ++i) {                                      \
                int row = wr * 64 + i * 16 + rl;                               \
                af[i] = *(const bf16x8*)(Al + row * 64 + ((kh ^ ((row >> 1) & 3)) << 4)); \
                int col = wc * 64 + i * 16 + rl;                               \
                bfr[i] = *(const bf16x8*)(Bl + col * 64 + ((kh ^ ((col >> 1) & 3)) << 4)); \
            }                                                                  \
            _Pragma("unroll")                                                  \
            for (int i = 0; i < 4; ++i)                                        \
                _Pragma("unroll")                                              \
                for (int j = 0; j < 4; ++j)                                    \
                    acc[i][j] = MFMA16(af[i], bfr[j], acc[i][j]);              \
            __syncthreads();                                                   \
        }                                                                      \
    }

// QKV: A = xT, B = Wt[z].  Q scaled by DH^-0.5*log2(e) (softmax scale
// folded in).  Q/K bf16 [B][H][S][DH]; V bf16 transposed [B][H][DH][S].
__global__ __launch_bounds__(256) void qkv_mm(
    const unsigned short* __restrict__ xT, const unsigned short* __restrict__ Wt,
    const float* __restrict__ bq, const float* __restrict__ bk,
    const float* __restrict__ bv,
    unsigned short* __restrict__ Qb, unsigned short* __restrict__ Kb,
    unsigned short* __restrict__ Vb)
{
    const int z = blockIdx.z;
    const unsigned short* Bt = Wt + (size_t)z * EMB * CC;
    const float* bias = (z == 0) ? bq : (z == 1) ? bk : bv;
    const int m0 = blockIdx.x * 128, n0 = blockIdx.y * 128;

    GEMM_CORE(xT, Bt)

    if (z == 2) {
        // V^T: [B][H][DH][S], 4 consecutive s -> vector store
        #pragma unroll
        for (int i = 0; i < 4; ++i) {
            #pragma unroll
            for (int j = 0; j < 4; ++j) {
                int n = n0 + wc * 64 + j * 16 + rl;
                int h = n >> 6, d = n & 63;
                float bi = bias[n];
                int mb = m0 + wr * 64 + i * 16 + kh * 4;
                int b = mb >> 10, s = mb & 1023;
                bf16x4 o;
                #pragma unroll
                for (int r = 0; r < 4; ++r) o[r] = (__bf16)(acc[i][j][r] + bi);
                *(bf16x4*)((__bf16*)Vb + (((size_t)(b * HEADS + h)) * DH + d) * SS + s) = o;
            }
        }
    } else {
        unsigned short* outp = (z == 0) ? Qb : Kb;
        const float qs = (z == 0) ? 0.1803368801f : 1.0f;   // 0.125*log2(e)
        #pragma unroll
        for (int i = 0; i < 4; ++i) {
            #pragma unroll
            for (int j = 0; j < 4; ++j) {
                int n = n0 + wc * 64 + j * 16 + rl;
                int h = n >> 6, d = n & 63;
                float bi = bias[n];
                #pragma unroll
                for (int r = 0; r < 4; ++r) {
                    int m = m0 + wr * 64 + i * 16 + kh * 4 + r;
                    int b = m >> 10, s = m & 1023;
                    ((__bf16*)outp)[(((size_t)(b * HEADS + h)) * SS + s) * DH + d] =
                        (__bf16)((acc[i][j][r] + bi) * qs);
                }
            }
        }
    }
}

// proj: A = AO bf16, B = Wot; out Y **bf16** [B][C][S] = acc + bo + residual.
__global__ __launch_bounds__(256) void proj_mm(
    const unsigned short* __restrict__ AO, const unsigned short* __restrict__ Wot,
    const float* __restrict__ bo, const float* __restrict__ x,
    unsigned short* __restrict__ Yb)
{
    const int m0 = blockIdx.x * 128, n0 = blockIdx.y * 128;

    GEMM_CORE(AO, Wot)

    #pragma unroll
    for (int i = 0; i < 4; ++i) {
        #pragma unroll
        for (int j = 0; j < 4; ++j) {
            int n = n0 + wc * 64 + j * 16 + rl;
            float bi = bo[n];
            int mb = m0 + wr * 64 + i * 16 + kh * 4;
            int b = mb >> 10, s = mb & 1023;
            const float4 xr = *(const float4*)(x + ((size_t)b * CC + n) * SS + s);
            bf16x4 o;
            o[0] = (__bf16)(acc[i][j][0] + bi + xr.x);
            o[1] = (__bf16)(acc[i][j][1] + bi + xr.y);
            o[2] = (__bf16)(acc[i][j][2] + bi + xr.z);
            o[3] = (__bf16)(acc[i][j][3] + bi + xr.w);
            *(bf16x4*)((__bf16*)Yb + ((size_t)b * CC + n) * SS + s) = o;
        }
    }
}

// ---------------------------------------------------------------------------
// MFMA flash attention v4: NO K/V LDS staging.  K+V per (b,h) is 256 KB and
// L2-resident (XCD remap keeps all 8 q-blocks of a (b,h) on one XCD), so MFMA
// fragments are loaded DIRECTLY from global (per-lane 16B, L2 hits) —
// m168->m169 pattern.  Zero __syncthreads in the main loop; LDS holds only
// the per-wave P tile (2 KB/wave).  16 q-rows/wave, 1024 blocks.
// ---------------------------------------------------------------------------
__global__ __launch_bounds__(256) void attn_mfma(
    const unsigned short* __restrict__ Q, const unsigned short* __restrict__ K,
    const unsigned short* __restrict__ V, unsigned short* __restrict__ Aout)
{
    __shared__ __align__(16) char lds[8192];

    // XCD-aware remap: 16 q-blocks of one (b,h) stay on one XCD.
    const int wg  = blockIdx.x;          // 0..1023
    const int xcd = wg & 7;
    const int idx = wg >> 3;             // 0..127
    const int pair = xcd * 8 + (idx >> 4);   // 0..63
    const int qb   = idx & 15;
    const int h = pair & 7;
    const int b = pair >> 3;
    const int q0 = qb * 64;

    const size_t kbase = ((size_t)b * HEADS + h) * SS * DH;   // Q,K layout
    const size_t vbase = ((size_t)b * HEADS + h) * DH * SS;   // V^T layout

    const int t  = threadIdx.x;
    const int w  = t >> 6;
    const int l  = t & 63;
    const int g  = l >> 4;
    const int qi = l & 15;
    char* Pl = lds + w * 2048;

    // Q fragments resident in registers (scale pre-folded by qkv_mm)
    bf16x8 qf[2];
    {
        const unsigned short* qrow = Q + kbase + (size_t)(q0 + w * 16 + qi) * DH;
        qf[0] = *(const bf16x8*)(qrow + g * 8);
        qf[1] = *(const bf16x8*)(qrow + 32 + g * 8);
    }

    f32x4 O[4] = {};
    float m2 = -1e30f, lsum = 0.f;

    #pragma unroll 1
    for (int kt = 0; kt < 16; ++kt) {
        // ---- K fragments straight from global (L2): row = kt*64+tt*16+qi ----
        const unsigned short* kp = K + kbase + (size_t)(kt * 64 + qi) * DH + g * 8;
        bf16x8 kf[4][2];
        #pragma unroll
        for (int tt = 0; tt < 4; ++tt) {
            kf[tt][0] = *(const bf16x8*)(kp + tt * 16 * DH);
            kf[tt][1] = *(const bf16x8*)(kp + tt * 16 * DH + 32);
        }
        // ---- V^T fragments issued early: row d = dt*16+qi, col kt*64+hh*32+g*8
        const unsigned short* vp = V + vbase + (size_t)qi * SS + kt * 64 + g * 8;
        bf16x8 vf[4][2];
        #pragma unroll
        for (int dt = 0; dt < 4; ++dt) {
            vf[dt][0] = *(const bf16x8*)(vp + (size_t)(dt * 16) * SS);
            vf[dt][1] = *(const bf16x8*)(vp + (size_t)(dt * 16) * SS + 32);
        }

        // ---- QK^T swapped: st[tt][r] = S^T[kk=tt*16+g*4+r][q=qi] ----
        f32x4 st[4] = {};
        __builtin_amdgcn_s_setprio(1);
        #pragma unroll
        for (int tt = 0; tt < 4; ++tt) {
            st[tt] = MFMA16(kf[tt][0], qf[0], st[tt]);
            st[tt] = MFMA16(kf[tt][1], qf[1], st[tt]);
        }
        __builtin_amdgcn_s_setprio(0);

        // ---- softmax (exp2 domain, defer-max THR=8) ----
        float pmax = -1e30f;
        #pragma unroll
        for (int tt = 0; tt < 4; ++tt)
            #pragma unroll
            for (int r = 0; r < 4; ++r)
                pmax = fmaxf(pmax, st[tt][r]);
        if (!__all(pmax <= m2 + 8.0f)) {
            float gm = fmaxf(pmax, __shfl_xor(pmax, 16));
            gm = fmaxf(gm, __shfl_xor(gm, 32));
            float newm = fmaxf(m2, gm);
            float alpha = EXP2F(m2 - newm);
            #pragma unroll
            for (int dt = 0; dt < 4; ++dt)
                #pragma unroll
                for (int r = 0; r < 4; ++r) O[dt][r] *= alpha;
            lsum *= alpha;
            m2 = newm;
        }
        #pragma unroll
        for (int tt = 0; tt < 4; ++tt) {
            bf16x4 pk;
            #pragma unroll
            for (int r = 0; r < 4; ++r) {
                float p = EXP2F(st[tt][r] - m2);
                lsum += p;
                pk[r] = (__bf16)p;
            }
            *(bf16x4*)(Pl + qi * 128 + ((tt * 32 + g * 8) ^ ((qi & 7) << 4))) = pk;
        }

        // ---- PV: O^T[d][q] += V^T[d][k] P^T[k][q]  (per-wave P, no barrier)
        bf16x8 pf0 = *(const bf16x8*)(Pl + qi * 128 + ((g * 16) ^ ((qi & 7) << 4)));
        bf16x8 pf1 = *(const bf16x8*)(Pl + qi * 128 + ((64 + g * 16) ^ ((qi & 7) << 4)));
        __builtin_amdgcn_s_setprio(1);
        #pragma unroll
        for (int dt = 0; dt < 4; ++dt) {
            O[dt] = MFMA16(vf[dt][0], pf0, O[dt]);
            O[dt] = MFMA16(vf[dt][1], pf1, O[dt]);
        }
        __builtin_amdgcn_s_setprio(0);
    }

    // ---- epilogue ----
    lsum += __shfl_xor(lsum, 16);
    lsum += __shfl_xor(lsum, 32);
    const float inv = __builtin_amdgcn_rcpf(lsum);
    unsigned short* orow = Aout + ((size_t)b * SS + q0 + w * 16 + qi) * EMB + h * DH;
    #pragma unroll
    for (int dt = 0; dt < 4; ++dt) {
        bf16x4 o;
        #pragma unroll
        for (int r = 0; r < 4; ++r) o[r] = (__bf16)(O[dt][r] * inv);
        *(bf16x4*)((__bf16*)orow + dt * 16 + g * 4) = o;
    }
}

// ---------------------------------------------------------------------------
// GroupNorm: Y bf16 [B][C][S] read ONCE into LDS (32KB/group), stats from
// LDS, normalize from LDS, fp32 out.  One block per (group, batch).
// ---------------------------------------------------------------------------
__global__ __launch_bounds__(256) void gnorm3(
    const __bf16* __restrict__ Yb, const float* __restrict__ gw,
    const float* __restrict__ gb, float* __restrict__ out)
{
    __shared__ __align__(16) __bf16 ybuf[CPG * SS];   // 32 KB
    __shared__ float red[8];
    __shared__ float stats[2];

    const int grp = blockIdx.x;
    const int b   = blockIdx.y;
    const int t   = threadIdx.x;
    const size_t base = ((size_t)b * CC + grp * CPG) * SS;   // 16384 elems
    const __bf16* src = Yb + base;

    float sum = 0.f, sq = 0.f;
    #pragma unroll
    for (int i = 0; i < 8; ++i) {
        int off = i * 2048 + t * 8;
        bf16x8 v = *(const bf16x8*)(src + off);
        *(bf16x8*)(ybuf + off) = v;
        #pragma unroll
        for (int j = 0; j < 8; ++j) {
            float f = (float)v[j];
            sum += f; sq += f * f;
        }
    }
    #pragma unroll
    for (int off = 32; off; off >>= 1) {
        sum += __shfl_down(sum, off);
        sq  += __shfl_down(sq, off);
    }
    const int wid = t >> 6;
    if ((t & 63) == 0) { red[wid] = sum; red[4 + wid] = sq; }
    __syncthreads();
    if (t == 0) {
        float s1 = red[0] + red[1] + red[2] + red[3];
        float s2 = red[4] + red[5] + red[6] + red[7];
        float mean = s1 / (float)(CPG * SS);
        float var  = s2 / (float)(CPG * SS) - mean * mean;
        stats[0] = mean;
        stats[1] = rsqrtf(var + EPS);
    }
    __syncthreads();
    const float mean = stats[0], rs = stats[1];

    #pragma unroll
    for (int i = 0; i < 8; ++i) {
        int off = i * 2048 + t * 8;
        int ch = grp * CPG + (off >> 10);
        float wgt = gw[ch] * rs, bet = gb[ch] - mean * rs * gw[ch];
        bf16x8 v = *(const bf16x8*)(ybuf + off);
        float4 o0, o1;
        o0.x = (float)v[0] * wgt + bet; o0.y = (float)v[1] * wgt + bet;
        o0.z = (float)v[2] * wgt + bet; o0.w = (float)v[3] * wgt + bet;
        o1.x = (float)v[4] * wgt + bet; o1.y = (float)v[5] * wgt + bet;
        o1.z = (float)v[6] * wgt + bet; o1.w = (float)v[7] * wgt + bet;
        *(float4*)(out + base + off)     = o0;
        *(float4*)(out + base + off + 4) = o1;
    }
}

// ---------------------------------------------------------------------------
extern "C" void kernel_launch(void* const* d_in, const int* in_sizes, int n_in,
                              void* d_out, int out_size, void* d_ws, size_t ws_size,
                              hipStream_t stream) {
    const float* x   = (const float*)d_in[0];
    const float* Wq  = (const float*)d_in[1];
    const float* bq  = (const float*)d_in[2];
    const float* Wk  = (const float*)d_in[3];
    const float* bk  = (const float*)d_in[4];
    const float* Wv  = (const float*)d_in[5];
    const float* bv  = (const float*)d_in[6];
    const float* Wo  = (const float*)d_in[7];
    const float* bo  = (const float*)d_in[8];
    const float* gnw = (const float*)d_in[9];
    const float* gnb = (const float*)d_in[10];
    float* out = (float*)d_out;
    char* ws  = (char*)d_ws;

    unsigned short* xT  = (unsigned short*)(ws);                       //  8 MB
    unsigned short* Wt  = (unsigned short*)(ws + 8388608);             //  2 MB
    unsigned short* Qb  = (unsigned short*)(ws + 10485760);            //  8 MB
    unsigned short* Kb  = (unsigned short*)(ws + 18874368);            //  8 MB
    unsigned short* Vb  = (unsigned short*)(ws + 27262976);            //  8 MB (V^T)
    unsigned short* AO  = (unsigned short*)(ws + 35651584);            //  8 MB
    unsigned short* Yb  = (unsigned short*)(ws + 44040192);            //  8 MB (bf16)

    prep_all<<<dim3(5120), 256, 0, stream>>>(x, Wq, Wk, Wv, Wo, xT, Wt);
    qkv_mm<<<dim3(64, 4, 3), 256, 0, stream>>>(xT, Wt, bq, bk, bv, Qb, Kb, Vb);
    attn_mfma<<<dim3(1024), 256, 0, stream>>>(Qb, Kb, Vb, AO);
    proj_mm<<<dim3(64, 4), 256, 0, stream>>>(AO, Wt + (size_t)3 * EMB * CC, bo, x, Yb);
    gnorm3<<<dim3(32, 8), 256, 0, stream>>>((const __bf16*)Yb, gnw, gnb, out);
}

// Round 8
// 91.099 us; speedup vs baseline: 1.8542x; 1.8542x over previous
//
#include <hip/hip_runtime.h>

#define BB 8
#define CC 512
#define SS 1024   // H*W
#define EMB 512
#define HEADS 8
#define DH 64
#define GROUPS 32
#define CPG 16
#define EPS 1e-5f

typedef __bf16 bf16x8 __attribute__((ext_vector_type(8)));
typedef __bf16 bf16x4 __attribute__((ext_vector_type(4)));
typedef float f32x4 __attribute__((ext_vector_type(4)));
typedef unsigned short u16x4 __attribute__((ext_vector_type(4)));

__device__ inline unsigned short f2bf(float f) {
    union { float f; unsigned u; } c; c.f = f;
    unsigned u = c.u + 0x7FFF + ((c.u >> 16) & 1);   // RNE
    return (unsigned short)(u >> 16);
}

#if defined(__has_builtin)
#if __has_builtin(__builtin_amdgcn_exp2f)
#define EXP2F(x) __builtin_amdgcn_exp2f(x)
#endif
#endif
#ifndef EXP2F
#define EXP2F(x) __expf(0.69314718f * (x))
#endif

#define MFMA16(a, b, c) __builtin_amdgcn_mfma_f32_16x16x32_bf16((a), (b), (c), 0, 0, 0)
#define GLOAD_LDS16(g, s)                                                     \
    __builtin_amdgcn_global_load_lds(                                         \
        (const __attribute__((address_space(1))) void*)(g),                   \
        (__attribute__((address_space(3))) void*)(s), 16, 0, 0)

// ---------------------------------------------------------------------------
// Prep (fused): blocks 0..4095 transpose x -> xT bf16; 4096..5119 transpose
// the four weight matrices -> Wt bf16 (K-major).
// ---------------------------------------------------------------------------
__global__ __launch_bounds__(256) void prep_all(
    const float* __restrict__ x,
    const float* __restrict__ Wq, const float* __restrict__ Wk,
    const float* __restrict__ Wv, const float* __restrict__ Wo,
    unsigned short* __restrict__ xT, unsigned short* __restrict__ Wt)
{
    __shared__ float tile[32][33];
    const int t = threadIdx.x;

    if (blockIdx.x < 4096) {
        const int i  = blockIdx.x;
        const int s0 = (i & 31) * 32;
        const int c0 = ((i >> 5) & 15) * 32;
        const int b  = i >> 9;
        {
            int c = t >> 3, s4 = (t & 7) * 4;
            float4 v = *(const float4*)(x + ((size_t)b * CC + c0 + c) * SS + s0 + s4);
            tile[c][s4] = v.x; tile[c][s4 + 1] = v.y;
            tile[c][s4 + 2] = v.z; tile[c][s4 + 3] = v.w;
        }
        __syncthreads();
        {
            int sr = t >> 3, c4 = (t & 7) * 4;
            u16x4 o;
            #pragma unroll
            for (int i2 = 0; i2 < 4; ++i2) o[i2] = f2bf(tile[c4 + i2][sr]);
            *(u16x4*)(xT + ((size_t)(b << 10) + s0 + sr) * CC + c0 + c4) = o;
        }
    } else {
        const int i  = blockIdx.x - 4096;
        const int k0 = (i & 15) * 32;
        const int n0 = ((i >> 4) & 15) * 32;
        const int z  = i >> 8;
        const float* W = (z == 0) ? Wq : (z == 1) ? Wk : (z == 2) ? Wv : Wo;
        unsigned short* dst = Wt + (size_t)z * EMB * CC;
        {
            int k = t >> 3, n4 = (t & 7) * 4;
            float4 v = *(const float4*)(W + (size_t)(k0 + k) * EMB + n0 + n4);
            tile[k][n4] = v.x; tile[k][n4 + 1] = v.y;
            tile[k][n4 + 2] = v.z; tile[k][n4 + 3] = v.w;
        }
        __syncthreads();
        {
            int n = t >> 3, k4 = (t & 7) * 4;
            u16x4 o;
            #pragma unroll
            for (int i2 = 0; i2 < 4; ++i2) o[i2] = f2bf(tile[k4 + i2][n]);
            *(u16x4*)(dst + (size_t)(n0 + n) * CC + k0 + k4) = o;
        }
    }
}

// ---------------------------------------------------------------------------
// MFMA GEMM core: 128x128 tile, BK=32, 4 waves 2x2, dbuf LDS via
// global_load_lds(16B), slot-XOR swizzle (pre-swizzled source).
// ---------------------------------------------------------------------------
#define GEMM_CORE(Aptr, Bptr)                                                  \
    __shared__ __align__(16) char lds[32768];                                  \
    const int t = threadIdx.x, w = t >> 6, l = t & 63;                         \
    const int wr = w >> 1, wc = w & 1;                                         \
    const int rl = l & 15, kh = l >> 4;                                        \
    f32x4 acc[4][4] = {};                                                      \
    {                                                                          \
        const int srow = w * 32 + (l >> 2);                                    \
        const int sslot = (l & 3) ^ ((srow >> 1) & 3);                         \
        const char* Ag0 = (const char*)(Aptr) + (size_t)(m0 + srow) * 1024 + sslot * 16;      \
        const char* Ag1 = (const char*)(Aptr) + (size_t)(m0 + srow + 16) * 1024 + (((l & 3) ^ (((srow + 16) >> 1) & 3)) * 16); \
        const char* Bg0 = (const char*)(Bptr) + (size_t)(n0 + srow) * 1024 + sslot * 16;      \
        const char* Bg1 = (const char*)(Bptr) + (size_t)(n0 + srow + 16) * 1024 + (((l & 3) ^ (((srow + 16) >> 1) & 3)) * 16); \
        for (int kt = 0; kt < 16; ++kt) {                                      \
            if (kt == 0) {                                                     \
                GLOAD_LDS16(Ag0, lds + w * 2048);                              \
                GLOAD_LDS16(Ag1, lds + w * 2048 + 1024);                       \
                GLOAD_LDS16(Bg0, lds + 8192 + w * 2048);                       \
                GLOAD_LDS16(Bg1, lds + 8192 + w * 2048 + 1024);                \
                __syncthreads();                                               \
            }                                                                  \
            const int buf = kt & 1;                                            \
            if (kt < 15) {                                                     \
                const int kb = (kt + 1) * 64;                                  \
                char* Al = lds + (buf ^ 1) * 16384;                            \
                char* Bl = Al + 8192;                                          \
                GLOAD_LDS16(Ag0 + kb, Al + w * 2048);                          \
                GLOAD_LDS16(Ag1 + kb, Al + w * 2048 + 1024);                   \
                GLOAD_LDS16(Bg0 + kb, Bl + w * 2048);                          \
                GLOAD_LDS16(Bg1 + kb, Bl + w * 2048 + 1024);                   \
            }                                                                  \
            const char* Al = lds + buf * 16384;                                \
            const char* Bl = Al + 8192;                                        \
            bf16x8 af[4], bfr[4];                                              \
            _Pragma("unroll")                                                  \
            for (int i = 0; i < 4; ++i) {                                      \
                int row = wr * 64 + i * 16 + rl;                               \
                af[i] = *(const bf16x8*)(Al + row * 64 + ((kh ^ ((row >> 1) & 3)) << 4)); \
                int col = wc * 64 + i * 16 + rl;                               \
                bfr[i] = *(const bf16x8*)(Bl + col * 64 + ((kh ^ ((col >> 1) & 3)) << 4)); \
            }                                                                  \
            _Pragma("unroll")                                                  \
            for (int i = 0; i < 4; ++i)                                        \
                _Pragma("unroll")                                              \
                for (int j = 0; j < 4; ++j)                                    \
                    acc[i][j] = MFMA16(af[i], bfr[j], acc[i][j]);              \
            __syncthreads();                                                   \
        }                                                                      \
    }

// QKV: A = xT, B = Wt[z].  Q scaled by DH^-0.5*log2(e) (softmax scale
// folded in).  Q/K bf16 [B][H][S][DH]; V bf16 transposed [B][H][DH][S].
__global__ __launch_bounds__(256) void qkv_mm(
    const unsigned short* __restrict__ xT, const unsigned short* __restrict__ Wt,
    const float* __restrict__ bq, const float* __restrict__ bk,
    const float* __restrict__ bv,
    unsigned short* __restrict__ Qb, unsigned short* __restrict__ Kb,
    unsigned short* __restrict__ Vb)
{
    const int z = blockIdx.z;
    const unsigned short* Bt = Wt + (size_t)z * EMB * CC;
    const float* bias = (z == 0) ? bq : (z == 1) ? bk : bv;
    const int m0 = blockIdx.x * 128, n0 = blockIdx.y * 128;

    GEMM_CORE(xT, Bt)

    if (z == 2) {
        // V^T: [B][H][DH][S], 4 consecutive s -> vector store
        #pragma unroll
        for (int i = 0; i < 4; ++i) {
            #pragma unroll
            for (int j = 0; j < 4; ++j) {
                int n = n0 + wc * 64 + j * 16 + rl;
                int h = n >> 6, d = n & 63;
                float bi = bias[n];
                int mb = m0 + wr * 64 + i * 16 + kh * 4;
                int b = mb >> 10, s = mb & 1023;
                bf16x4 o;
                #pragma unroll
                for (int r = 0; r < 4; ++r) o[r] = (__bf16)(acc[i][j][r] + bi);
                *(bf16x4*)((__bf16*)Vb + (((size_t)(b * HEADS + h)) * DH + d) * SS + s) = o;
            }
        }
    } else {
        unsigned short* outp = (z == 0) ? Qb : Kb;
        const float qs = (z == 0) ? 0.1803368801f : 1.0f;   // 0.125*log2(e)
        #pragma unroll
        for (int i = 0; i < 4; ++i) {
            #pragma unroll
            for (int j = 0; j < 4; ++j) {
                int n = n0 + wc * 64 + j * 16 + rl;
                int h = n >> 6, d = n & 63;
                float bi = bias[n];
                #pragma unroll
                for (int r = 0; r < 4; ++r) {
                    int m = m0 + wr * 64 + i * 16 + kh * 4 + r;
                    int b = m >> 10, s = m & 1023;
                    ((__bf16*)outp)[(((size_t)(b * HEADS + h)) * SS + s) * DH + d] =
                        (__bf16)((acc[i][j][r] + bi) * qs);
                }
            }
        }
    }
}

// proj: A = AO bf16, B = Wot; out Y bf16 [B][C][S] = acc + bo + residual.
__global__ __launch_bounds__(256) void proj_mm(
    const unsigned short* __restrict__ AO, const unsigned short* __restrict__ Wot,
    const float* __restrict__ bo, const float* __restrict__ x,
    unsigned short* __restrict__ Yb)
{
    const int m0 = blockIdx.x * 128, n0 = blockIdx.y * 128;

    GEMM_CORE(AO, Wot)

    #pragma unroll
    for (int i = 0; i < 4; ++i) {
        #pragma unroll
        for (int j = 0; j < 4; ++j) {
            int n = n0 + wc * 64 + j * 16 + rl;
            float bi = bo[n];
            int mb = m0 + wr * 64 + i * 16 + kh * 4;
            int b = mb >> 10, s = mb & 1023;
            const float4 xr = *(const float4*)(x + ((size_t)b * CC + n) * SS + s);
            bf16x4 o;
            o[0] = (__bf16)(acc[i][j][0] + bi + xr.x);
            o[1] = (__bf16)(acc[i][j][1] + bi + xr.y);
            o[2] = (__bf16)(acc[i][j][2] + bi + xr.z);
            o[3] = (__bf16)(acc[i][j][3] + bi + xr.w);
            *(bf16x4*)((__bf16*)Yb + ((size_t)b * CC + n) * SS + s) = o;
        }
    }
}

// ---------------------------------------------------------------------------
// MFMA flash attention v5.  KVBLK=64, 4 waves x 32 q-rows.
//  - K fragments DIRECT from global (coalesced lane pattern qi*128+g*16,
//    2KB/instr) with 1-tile-ahead register prefetch (kfA/kfB ping-pong) --
//    removes K from the LDS pipe (the R6 bottleneck).
//  - V^T staged via global_load_lds dbuf (pre-swizzled source) as R6 --
//    direct V loads would be stride-2048 scatter (the R7 failure).
//  - per-wave P LDS tile; defer-max softmax in exp2 domain (scale folded
//    into Q); tree-max; setprio on MFMA clusters; XCD remap.
// LDS: V dbuf 2x8KB + P 4x4KB = 32KB.
// ---------------------------------------------------------------------------
__global__ __launch_bounds__(256) void attn_mfma(
    const unsigned short* __restrict__ Q, const unsigned short* __restrict__ K,
    const unsigned short* __restrict__ V, unsigned short* __restrict__ Aout)
{
    __shared__ __align__(16) char lds[32768];

    // XCD-aware remap: 8 q-blocks of one (b,h) stay on one XCD.
    const int wg  = blockIdx.x;          // 0..511
    const int xcd = wg & 7;
    const int idx = wg >> 3;             // 0..63
    const int pair = xcd * 8 + (idx >> 3);   // 0..63
    const int qb   = idx & 7;
    const int h = pair & 7;
    const int b = pair >> 3;
    const int q0 = qb * 128;

    const size_t kbase = ((size_t)b * HEADS + h) * SS * DH;   // Q,K layout
    const size_t vbase = ((size_t)b * HEADS + h) * DH * SS;   // V^T layout

    const int t  = threadIdx.x;
    const int w  = t >> 6;
    const int l  = t & 63;
    const int g  = l >> 4;
    const int qi = l & 15;
    char* Pl = lds + 16384 + w * 4096;

    // Q fragments resident in registers: 2 q-columns (u) x 2 k-halves
    bf16x8 qf[2][2];
    #pragma unroll
    for (int u = 0; u < 2; ++u) {
        const unsigned short* qrow =
            Q + kbase + (size_t)(q0 + w * 32 + u * 16 + qi) * DH;
        qf[u][0] = *(const bf16x8*)(qrow + g * 8);
        qf[u][1] = *(const bf16x8*)(qrow + 32 + g * 8);
    }

    // V staging (pre-swizzled source, linear LDS dest)
    const int srow = t >> 3;             // 0..31
    const int seg  = t & 7;
    const unsigned short* vg0 = V + vbase + (size_t)srow * SS + ((seg ^ (srow & 7)) * 8);

    // K direct-global lane base: element K[row][g*8 + j], row = kt*64+tt*16+qi
    const unsigned short* kg = K + kbase + (size_t)qi * DH + g * 8;

#define STAGE_V(bb, ktn)                                                       \
    GLOAD_LDS16(vg0 + (ktn) * 64, lds + (bb) + t * 16);                        \
    GLOAD_LDS16(vg0 + (ktn) * 64 + 32 * SS, lds + (bb) + 4096 + t * 16);

#define LOAD_K(dst, ktn)                                                       \
    _Pragma("unroll")                                                          \
    for (int tt = 0; tt < 4; ++tt) {                                           \
        const unsigned short* kp = kg + (size_t)((ktn) * 64 + tt * 16) * DH;   \
        dst[tt][0] = *(const bf16x8*)(kp);                                     \
        dst[tt][1] = *(const bf16x8*)(kp + 32);                                \
    }

    f32x4 O[4][2] = {};
    float m2[2]   = {-1e30f, -1e30f};
    float lsum[2] = {0.f, 0.f};

    bf16x8 kfA[4][2], kfB[4][2];
    LOAD_K(kfA, 0)
    STAGE_V(0, 0)
    __syncthreads();

#define TILE_BODY(kfC, kfN, kt, bb)                                            \
    {                                                                          \
        if ((kt) < 15) { LOAD_K(kfN, (kt) + 1) STAGE_V((bb) ^ 8192, (kt) + 1) }\
        const char* Vl = lds + (bb);                                           \
        f32x4 st[4][2] = {};                                                   \
        __builtin_amdgcn_s_setprio(1);                                         \
        _Pragma("unroll")                                                      \
        for (int tt = 0; tt < 4; ++tt) {                                       \
            _Pragma("unroll")                                                  \
            for (int u = 0; u < 2; ++u) {                                      \
                st[tt][u] = MFMA16(kfC[tt][0], qf[u][0], st[tt][u]);           \
                st[tt][u] = MFMA16(kfC[tt][1], qf[u][1], st[tt][u]);           \
            }                                                                  \
        }                                                                      \
        __builtin_amdgcn_s_setprio(0);                                         \
        _Pragma("unroll")                                                      \
        for (int u = 0; u < 2; ++u) {                                          \
            float a0 = fmaxf(fmaxf(st[0][u][0], st[0][u][1]),                  \
                             fmaxf(st[0][u][2], st[0][u][3]));                 \
            float a1 = fmaxf(fmaxf(st[1][u][0], st[1][u][1]),                  \
                             fmaxf(st[1][u][2], st[1][u][3]));                 \
            float a2 = fmaxf(fmaxf(st[2][u][0], st[2][u][1]),                  \
                             fmaxf(st[2][u][2], st[2][u][3]));                 \
            float a3 = fmaxf(fmaxf(st[3][u][0], st[3][u][1]),                  \
                             fmaxf(st[3][u][2], st[3][u][3]));                 \
            float pmax = fmaxf(fmaxf(a0, a1), fmaxf(a2, a3));                  \
            if (!__all(pmax <= m2[u] + 8.0f)) {                                \
                float gm = fmaxf(pmax, __shfl_xor(pmax, 16));                  \
                gm = fmaxf(gm, __shfl_xor(gm, 32));                            \
                float newm = fmaxf(m2[u], gm);                                 \
                float alpha = EXP2F(m2[u] - newm);                             \
                _Pragma("unroll")                                              \
                for (int dt = 0; dt < 4; ++dt)                                 \
                    _Pragma("unroll")                                          \
                    for (int r = 0; r < 4; ++r) O[dt][u][r] *= alpha;          \
                lsum[u] *= alpha;                                              \
                m2[u] = newm;                                                  \
            }                                                                  \
            float tl[4];                                                       \
            _Pragma("unroll")                                                  \
            for (int tt = 0; tt < 4; ++tt) {                                   \
                bf16x4 pk;                                                     \
                float p0 = EXP2F(st[tt][u][0] - m2[u]);                        \
                float p1 = EXP2F(st[tt][u][1] - m2[u]);                        \
                float p2 = EXP2F(st[tt][u][2] - m2[u]);                        \
                float p3 = EXP2F(st[tt][u][3] - m2[u]);                        \
                pk[0] = (__bf16)p0; pk[1] = (__bf16)p1;                        \
                pk[2] = (__bf16)p2; pk[3] = (__bf16)p3;                        \
                tl[tt] = (p0 + p1) + (p2 + p3);                                \
                *(bf16x4*)(Pl + u * 2048 + qi * 128 +                          \
                           ((tt * 32 + g * 8) ^ ((qi & 7) << 4))) = pk;        \
            }                                                                  \
            lsum[u] += (tl[0] + tl[1]) + (tl[2] + tl[3]);                      \
        }                                                                      \
        bf16x8 pf[2][2];                                                       \
        _Pragma("unroll")                                                      \
        for (int u = 0; u < 2; ++u)                                            \
            _Pragma("unroll")                                                  \
            for (int hh = 0; hh < 2; ++hh)                                     \
                pf[u][hh] = *(const bf16x8*)(Pl + u * 2048 + qi * 128 +        \
                             ((hh * 64 + g * 16) ^ ((qi & 7) << 4)));          \
        __builtin_amdgcn_s_setprio(1);                                         \
        _Pragma("unroll")                                                      \
        for (int dt = 0; dt < 4; ++dt) {                                       \
            int d = dt * 16 + qi;                                              \
            bf16x8 vf0 = *(const bf16x8*)(Vl + d * 128 + ((g * 16) ^ ((d & 7) << 4)));       \
            bf16x8 vf1 = *(const bf16x8*)(Vl + d * 128 + ((64 + g * 16) ^ ((d & 7) << 4)));  \
            _Pragma("unroll")                                                  \
            for (int u = 0; u < 2; ++u) {                                      \
                O[dt][u] = MFMA16(vf0, pf[u][0], O[dt][u]);                    \
                O[dt][u] = MFMA16(vf1, pf[u][1], O[dt][u]);                    \
            }                                                                  \
        }                                                                      \
        __builtin_amdgcn_s_setprio(0);                                         \
        __syncthreads();                                                       \
    }

    for (int kt = 0; kt < 16; kt += 2) {
        TILE_BODY(kfA, kfB, kt, 0)
        TILE_BODY(kfB, kfA, kt + 1, 8192)
    }

    // ---- epilogue ----
    #pragma unroll
    for (int u = 0; u < 2; ++u) {
        float ls = lsum[u];
        ls += __shfl_xor(ls, 16);
        ls += __shfl_xor(ls, 32);
        const float inv = __builtin_amdgcn_rcpf(ls);
        unsigned short* orow = Aout +
            ((size_t)b * SS + q0 + w * 32 + u * 16 + qi) * EMB + h * DH;
        #pragma unroll
        for (int dt = 0; dt < 4; ++dt) {
            bf16x4 o;
            #pragma unroll
            for (int r = 0; r < 4; ++r) o[r] = (__bf16)(O[dt][u][r] * inv);
            *(bf16x4*)((__bf16*)orow + dt * 16 + g * 4) = o;
        }
    }
#undef TILE_BODY
#undef STAGE_V
#undef LOAD_K
}

// ---------------------------------------------------------------------------
// GroupNorm: Y bf16 [B][C][S] read ONCE into LDS (32KB/group), stats from
// LDS, normalize from LDS, fp32 out.  One block per (group, batch).
// ---------------------------------------------------------------------------
__global__ __launch_bounds__(256) void gnorm3(
    const __bf16* __restrict__ Yb, const float* __restrict__ gw,
    const float* __restrict__ gb, float* __restrict__ out)
{
    __shared__ __align__(16) __bf16 ybuf[CPG * SS];   // 32 KB
    __shared__ float red[8];
    __shared__ float stats[2];

    const int grp = blockIdx.x;
    const int b   = blockIdx.y;
    const int t   = threadIdx.x;
    const size_t base = ((size_t)b * CC + grp * CPG) * SS;   // 16384 elems
    const __bf16* src = Yb + base;

    float sum = 0.f, sq = 0.f;
    #pragma unroll
    for (int i = 0; i < 8; ++i) {
        int off = i * 2048 + t * 8;
        bf16x8 v = *(const bf16x8*)(src + off);
        *(bf16x8*)(ybuf + off) = v;
        #pragma unroll
        for (int j = 0; j < 8; ++j) {
            float f = (float)v[j];
            sum += f; sq += f * f;
        }
    }
    #pragma unroll
    for (int off = 32; off; off >>= 1) {
        sum += __shfl_down(sum, off);
        sq  += __shfl_down(sq, off);
    }
    const int wid = t >> 6;
    if ((t & 63) == 0) { red[wid] = sum; red[4 + wid] = sq; }
    __syncthreads();
    if (t == 0) {
        float s1 = red[0] + red[1] + red[2] + red[3];
        float s2 = red[4] + red[5] + red[6] + red[7];
        float mean = s1 / (float)(CPG * SS);
        float var  = s2 / (float)(CPG * SS) - mean * mean;
        stats[0] = mean;
        stats[1] = rsqrtf(var + EPS);
    }
    __syncthreads();
    const float mean = stats[0], rs = stats[1];

    #pragma unroll
    for (int i = 0; i < 8; ++i) {
        int off = i * 2048 + t * 8;
        int ch = grp * CPG + (off >> 10);
        float wgt = gw[ch] * rs, bet = gb[ch] - mean * rs * gw[ch];
        bf16x8 v = *(const bf16x8*)(ybuf + off);
        float4 o0, o1;
        o0.x = (float)v[0] * wgt + bet; o0.y = (float)v[1] * wgt + bet;
        o0.z = (float)v[2] * wgt + bet; o0.w = (float)v[3] * wgt + bet;
        o1.x = (float)v[4] * wgt + bet; o1.y = (float)v[5] * wgt + bet;
        o1.z = (float)v[6] * wgt + bet; o1.w = (float)v[7] * wgt + bet;
        *(float4*)(out + base + off)     = o0;
        *(float4*)(out + base + off + 4) = o1;
    }
}

// ---------------------------------------------------------------------------
extern "C" void kernel_launch(void* const* d_in, const int* in_sizes, int n_in,
                              void* d_out, int out_size, void* d_ws, size_t ws_size,
                              hipStream_t stream) {
    const float* x   = (const float*)d_in[0];
    const float* Wq  = (const float*)d_in[1];
    const float* bq  = (const float*)d_in[2];
    const float* Wk  = (const float*)d_in[3];
    const float* bk  = (const float*)d_in[4];
    const float* Wv  = (const float*)d_in[5];
    const float* bv  = (const float*)d_in[6];
    const float* Wo  = (const float*)d_in[7];
    const float* bo  = (const float*)d_in[8];
    const float* gnw = (const float*)d_in[9];
    const float* gnb = (const float*)d_in[10];
    float* out = (float*)d_out;
    char* ws  = (char*)d_ws;

    unsigned short* xT  = (unsigned short*)(ws);                       //  8 MB
    unsigned short* Wt  = (unsigned short*)(ws + 8388608);             //  2 MB
    unsigned short* Qb  = (unsigned short*)(ws + 10485760);            //  8 MB
    unsigned short* Kb  = (unsigned short*)(ws + 18874368);            //  8 MB
    unsigned short* Vb  = (unsigned short*)(ws + 27262976);            //  8 MB (V^T)
    unsigned short* AO  = (unsigned short*)(ws + 35651584);            //  8 MB
    unsigned short* Yb  = (unsigned short*)(ws + 44040192);            //  8 MB (bf16)

    prep_all<<<dim3(5120), 256, 0, stream>>>(x, Wq, Wk, Wv, Wo, xT, Wt);
    qkv_mm<<<dim3(64, 4, 3), 256, 0, stream>>>(xT, Wt, bq, bk, bv, Qb, Kb, Vb);
    attn_mfma<<<dim3(512), 256, 0, stream>>>(Qb, Kb, Vb, AO);
    proj_mm<<<dim3(64, 4), 256, 0, stream>>>(AO, Wt + (size_t)3 * EMB * CC, bo, x, Yb);
    gnorm3<<<dim3(32, 8), 256, 0, stream>>>((const __bf16*)Yb, gnw, gnb, out);
}

// Round 9
// 88.187 us; speedup vs baseline: 1.9154x; 1.0330x over previous
//
#include <hip/hip_runtime.h>

#define BB 8
#define CC 512
#define SS 1024   // H*W
#define EMB 512
#define HEADS 8
#define DH 64
#define GROUPS 32
#define CPG 16
#define EPS 1e-5f

typedef __bf16 bf16x8 __attribute__((ext_vector_type(8)));
typedef __bf16 bf16x4 __attribute__((ext_vector_type(4)));
typedef float f32x4 __attribute__((ext_vector_type(4)));
typedef unsigned short u16x4 __attribute__((ext_vector_type(4)));
typedef unsigned u32x2 __attribute__((ext_vector_type(2)));
typedef unsigned u32x4 __attribute__((ext_vector_type(4)));

__device__ inline unsigned short f2bf(float f) {
    union { float f; unsigned u; } c; c.f = f;
    unsigned u = c.u + 0x7FFF + ((c.u >> 16) & 1);   // RNE
    return (unsigned short)(u >> 16);
}

#if defined(__has_builtin)
#if __has_builtin(__builtin_amdgcn_exp2f)
#define EXP2F(x) __builtin_amdgcn_exp2f(x)
#endif
#endif
#ifndef EXP2F
#define EXP2F(x) __expf(0.69314718f * (x))
#endif

#if defined(__has_builtin)
#if __has_builtin(__builtin_amdgcn_permlane32_swap) && __has_builtin(__builtin_amdgcn_permlane16_swap)
#define PERMLANE_P 1
#endif
#endif
#ifndef PERMLANE_P
#define PERMLANE_P 0
#endif

#define MFMA16(a, b, c) __builtin_amdgcn_mfma_f32_16x16x32_bf16((a), (b), (c), 0, 0, 0)
#define GLOAD_LDS16(g, s)                                                     \
    __builtin_amdgcn_global_load_lds(                                         \
        (const __attribute__((address_space(1))) void*)(g),                   \
        (__attribute__((address_space(3))) void*)(s), 16, 0, 0)

// ---------------------------------------------------------------------------
// Prep (fused): blocks 0..4095 transpose x -> xT bf16; 4096..5119 transpose
// the four weight matrices -> Wt bf16 (K-major).
// ---------------------------------------------------------------------------
__global__ __launch_bounds__(256) void prep_all(
    const float* __restrict__ x,
    const float* __restrict__ Wq, const float* __restrict__ Wk,
    const float* __restrict__ Wv, const float* __restrict__ Wo,
    unsigned short* __restrict__ xT, unsigned short* __restrict__ Wt)
{
    __shared__ float tile[32][33];
    const int t = threadIdx.x;

    if (blockIdx.x < 4096) {
        const int i  = blockIdx.x;
        const int s0 = (i & 31) * 32;
        const int c0 = ((i >> 5) & 15) * 32;
        const int b  = i >> 9;
        {
            int c = t >> 3, s4 = (t & 7) * 4;
            float4 v = *(const float4*)(x + ((size_t)b * CC + c0 + c) * SS + s0 + s4);
            tile[c][s4] = v.x; tile[c][s4 + 1] = v.y;
            tile[c][s4 + 2] = v.z; tile[c][s4 + 3] = v.w;
        }
        __syncthreads();
        {
            int sr = t >> 3, c4 = (t & 7) * 4;
            u16x4 o;
            #pragma unroll
            for (int i2 = 0; i2 < 4; ++i2) o[i2] = f2bf(tile[c4 + i2][sr]);
            *(u16x4*)(xT + ((size_t)(b << 10) + s0 + sr) * CC + c0 + c4) = o;
        }
    } else {
        const int i  = blockIdx.x - 4096;
        const int k0 = (i & 15) * 32;
        const int n0 = ((i >> 4) & 15) * 32;
        const int z  = i >> 8;
        const float* W = (z == 0) ? Wq : (z == 1) ? Wk : (z == 2) ? Wv : Wo;
        unsigned short* dst = Wt + (size_t)z * EMB * CC;
        {
            int k = t >> 3, n4 = (t & 7) * 4;
            float4 v = *(const float4*)(W + (size_t)(k0 + k) * EMB + n0 + n4);
            tile[k][n4] = v.x; tile[k][n4 + 1] = v.y;
            tile[k][n4 + 2] = v.z; tile[k][n4 + 3] = v.w;
        }
        __syncthreads();
        {
            int n = t >> 3, k4 = (t & 7) * 4;
            u16x4 o;
            #pragma unroll
            for (int i2 = 0; i2 < 4; ++i2) o[i2] = f2bf(tile[k4 + i2][n]);
            *(u16x4*)(dst + (size_t)(n0 + n) * CC + k0 + k4) = o;
        }
    }
}

// ---------------------------------------------------------------------------
// MFMA GEMM core: 128x128 tile, BK=32, 4 waves 2x2, dbuf LDS via
// global_load_lds(16B), slot-XOR swizzle (pre-swizzled source).
// ---------------------------------------------------------------------------
#define GEMM_CORE(Aptr, Bptr)                                                  \
    __shared__ __align__(16) char lds[32768];                                  \
    const int t = threadIdx.x, w = t >> 6, l = t & 63;                         \
    const int wr = w >> 1, wc = w & 1;                                         \
    const int rl = l & 15, kh = l >> 4;                                        \
    f32x4 acc[4][4] = {};                                                      \
    {                                                                          \
        const int srow = w * 32 + (l >> 2);                                    \
        const int sslot = (l & 3) ^ ((srow >> 1) & 3);                         \
        const char* Ag0 = (const char*)(Aptr) + (size_t)(m0 + srow) * 1024 + sslot * 16;      \
        const char* Ag1 = (const char*)(Aptr) + (size_t)(m0 + srow + 16) * 1024 + (((l & 3) ^ (((srow + 16) >> 1) & 3)) * 16); \
        const char* Bg0 = (const char*)(Bptr) + (size_t)(n0 + srow) * 1024 + sslot * 16;      \
        const char* Bg1 = (const char*)(Bptr) + (size_t)(n0 + srow + 16) * 1024 + (((l & 3) ^ (((srow + 16) >> 1) & 3)) * 16); \
        for (int kt = 0; kt < 16; ++kt) {                                      \
            if (kt == 0) {                                                     \
                GLOAD_LDS16(Ag0, lds + w * 2048);                              \
                GLOAD_LDS16(Ag1, lds + w * 2048 + 1024);                       \
                GLOAD_LDS16(Bg0, lds + 8192 + w * 2048);                       \
                GLOAD_LDS16(Bg1, lds + 8192 + w * 2048 + 1024);                \
                __syncthreads();                                               \
            }                                                                  \
            const int buf = kt & 1;                                            \
            if (kt < 15) {                                                     \
                const int kb = (kt + 1) * 64;                                  \
                char* Al = lds + (buf ^ 1) * 16384;                            \
                char* Bl = Al + 8192;                                          \
                GLOAD_LDS16(Ag0 + kb, Al + w * 2048);                          \
                GLOAD_LDS16(Ag1 + kb, Al + w * 2048 + 1024);                   \
                GLOAD_LDS16(Bg0 + kb, Bl + w * 2048);                          \
                GLOAD_LDS16(Bg1 + kb, Bl + w * 2048 + 1024);                   \
            }                                                                  \
            const char* Al = lds + buf * 16384;                                \
            const char* Bl = Al + 8192;                                        \
            bf16x8 af[4], bfr[4];                                              \
            _Pragma("unroll")                                                  \
            for (int i = 0; i < 4; ++i) {                                      \
                int row = wr * 64 + i * 16 + rl;                               \
                af[i] = *(const bf16x8*)(Al + row * 64 + ((kh ^ ((row >> 1) & 3)) << 4)); \
                int col = wc * 64 + i * 16 + rl;                               \
                bfr[i] = *(const bf16x8*)(Bl + col * 64 + ((kh ^ ((col >> 1) & 3)) << 4)); \
            }                                                                  \
            _Pragma("unroll")                                                  \
            for (int i = 0; i < 4; ++i)                                        \
                _Pragma("unroll")                                              \
                for (int j = 0; j < 4; ++j)                                    \
                    acc[i][j] = MFMA16(af[i], bfr[j], acc[i][j]);              \
            __syncthreads();                                                   \
        }                                                                      \
    }

// QKV: A = xT, B = Wt[z].  Q scaled by DH^-0.5*log2(e) (softmax scale
// folded in).  Q/K bf16 [B][H][S][DH]; V bf16 transposed [B][H][DH][S].
__global__ __launch_bounds__(256) void qkv_mm(
    const unsigned short* __restrict__ xT, const unsigned short* __restrict__ Wt,
    const float* __restrict__ bq, const float* __restrict__ bk,
    const float* __restrict__ bv,
    unsigned short* __restrict__ Qb, unsigned short* __restrict__ Kb,
    unsigned short* __restrict__ Vb)
{
    const int z = blockIdx.z;
    const unsigned short* Bt = Wt + (size_t)z * EMB * CC;
    const float* bias = (z == 0) ? bq : (z == 1) ? bk : bv;
    const int m0 = blockIdx.x * 128, n0 = blockIdx.y * 128;

    GEMM_CORE(xT, Bt)

    if (z == 2) {
        #pragma unroll
        for (int i = 0; i < 4; ++i) {
            #pragma unroll
            for (int j = 0; j < 4; ++j) {
                int n = n0 + wc * 64 + j * 16 + rl;
                int h = n >> 6, d = n & 63;
                float bi = bias[n];
                int mb = m0 + wr * 64 + i * 16 + kh * 4;
                int b = mb >> 10, s = mb & 1023;
                bf16x4 o;
                #pragma unroll
                for (int r = 0; r < 4; ++r) o[r] = (__bf16)(acc[i][j][r] + bi);
                *(bf16x4*)((__bf16*)Vb + (((size_t)(b * HEADS + h)) * DH + d) * SS + s) = o;
            }
        }
    } else {
        unsigned short* outp = (z == 0) ? Qb : Kb;
        const float qs = (z == 0) ? 0.1803368801f : 1.0f;   // 0.125*log2(e)
        #pragma unroll
        for (int i = 0; i < 4; ++i) {
            #pragma unroll
            for (int j = 0; j < 4; ++j) {
                int n = n0 + wc * 64 + j * 16 + rl;
                int h = n >> 6, d = n & 63;
                float bi = bias[n];
                #pragma unroll
                for (int r = 0; r < 4; ++r) {
                    int m = m0 + wr * 64 + i * 16 + kh * 4 + r;
                    int b = m >> 10, s = m & 1023;
                    ((__bf16*)outp)[(((size_t)(b * HEADS + h)) * SS + s) * DH + d] =
                        (__bf16)((acc[i][j][r] + bi) * qs);
                }
            }
        }
    }
}

// proj: A = AO bf16, B = Wot; out Y bf16 [B][C][S] = acc + bo + residual.
__global__ __launch_bounds__(256) void proj_mm(
    const unsigned short* __restrict__ AO, const unsigned short* __restrict__ Wot,
    const float* __restrict__ bo, const float* __restrict__ x,
    unsigned short* __restrict__ Yb)
{
    const int m0 = blockIdx.x * 128, n0 = blockIdx.y * 128;

    GEMM_CORE(AO, Wot)

    #pragma unroll
    for (int i = 0; i < 4; ++i) {
        #pragma unroll
        for (int j = 0; j < 4; ++j) {
            int n = n0 + wc * 64 + j * 16 + rl;
            float bi = bo[n];
            int mb = m0 + wr * 64 + i * 16 + kh * 4;
            int b = mb >> 10, s = mb & 1023;
            const float4 xr = *(const float4*)(x + ((size_t)b * CC + n) * SS + s);
            bf16x4 o;
            o[0] = (__bf16)(acc[i][j][0] + bi + xr.x);
            o[1] = (__bf16)(acc[i][j][1] + bi + xr.y);
            o[2] = (__bf16)(acc[i][j][2] + bi + xr.z);
            o[3] = (__bf16)(acc[i][j][3] + bi + xr.w);
            *(bf16x4*)((__bf16*)Yb + ((size_t)b * CC + n) * SS + s) = o;
        }
    }
}

// ---------------------------------------------------------------------------
// MFMA flash attention v6 = R6 structure (KVBLK=64, 4 waves x 32 q-rows,
// K + V^T staged via global_load_lds dbuf, pre-swizzled source, one barrier
// per tile, defer-max softmax, setprio, XCD remap) with the P round-trip
// moved OFF the LDS pipe: the kk 4<->8 regrouping between QK^T's C-layout
// and PV's B-operand is a 2-stage butterfly over the 4-lane group
// {qi, qi+16, qi+32, qi+48}: permlane32_swap (+-32) then permlane16_swap
// (+-16), both VALU.  Swap-direction conventions are runtime-self-probed so
// the kernel is correct under either ISA semantic.  LDS: 2 x 16KB = 32KB.
// ---------------------------------------------------------------------------
__global__ __launch_bounds__(256) void attn_mfma(
    const unsigned short* __restrict__ Q, const unsigned short* __restrict__ K,
    const unsigned short* __restrict__ V, unsigned short* __restrict__ Aout)
{
#if PERMLANE_P
    __shared__ __align__(16) char lds[32768];
#else
    __shared__ __align__(16) char lds[49152];
#endif

    // XCD-aware remap: 8 q-blocks of one (b,h) stay on one XCD.
    const int wg  = blockIdx.x;          // 0..511
    const int xcd = wg & 7;
    const int idx = wg >> 3;             // 0..63
    const int pair = xcd * 8 + (idx >> 3);   // 0..63
    const int qb   = idx & 7;
    const int h = pair & 7;
    const int b = pair >> 3;
    const int q0 = qb * 128;

    const size_t kbase = ((size_t)b * HEADS + h) * SS * DH;   // Q,K layout
    const size_t vbase = ((size_t)b * HEADS + h) * DH * SS;   // V^T layout

    const int t  = threadIdx.x;
    const int w  = t >> 6;
    const int l  = t & 63;
    const int g  = l >> 4;
    const int qi = l & 15;

#if PERMLANE_P
    // Self-probe swap-direction conventions (uniform, once).
    u32x2 pr32 = __builtin_amdgcn_permlane32_swap((unsigned)l, 1000u + (unsigned)l, false, false);
    const bool v32B = (__builtin_amdgcn_readfirstlane(pr32[0]) == 0u);
    u32x2 pr16 = __builtin_amdgcn_permlane16_swap((unsigned)l, 1000u + (unsigned)l, false, false);
    const bool v16B = (__builtin_amdgcn_readfirstlane(pr16[0]) == 1016u);
#else
    char* Pl = lds + 32768 + w * 4096;
#endif

    // Q fragments resident in registers: 2 q-columns (u) x 2 k-halves
    bf16x8 qf[2][2];
    #pragma unroll
    for (int u = 0; u < 2; ++u) {
        const unsigned short* qrow =
            Q + kbase + (size_t)(q0 + w * 32 + u * 16 + qi) * DH;
        qf[u][0] = *(const bf16x8*)(qrow + g * 8);
        qf[u][1] = *(const bf16x8*)(qrow + 32 + g * 8);
    }

    // staging addresses (pre-swizzled source, linear LDS dest)
    const int srow = t >> 3;             // 0..31
    const int seg  = t & 7;
    const unsigned short* kg0 = K + kbase + (size_t)srow * DH + ((seg ^ (srow & 7)) * 8);
    const unsigned short* vg0 = V + vbase + (size_t)srow * SS + ((seg ^ (srow & 7)) * 8);

#define ATTN_STAGE(bb, ktn)                                                    \
    GLOAD_LDS16(kg0 + (ktn) * 4096, lds + (bb) + t * 16);                      \
    GLOAD_LDS16(kg0 + (ktn) * 4096 + 2048, lds + (bb) + 4096 + t * 16);        \
    GLOAD_LDS16(vg0 + (ktn) * 64, lds + (bb) + 8192 + t * 16);                 \
    GLOAD_LDS16(vg0 + (ktn) * 64 + 32768, lds + (bb) + 12288 + t * 16);

    f32x4 O[4][2] = {};
    float m2[2]   = {-1e30f, -1e30f};
    float lsum[2] = {0.f, 0.f};

    int bufb = 0;
    ATTN_STAGE(0, 0)
    __syncthreads();

    for (int kt = 0; kt < 16; ++kt) {
        if (kt < 15) { ATTN_STAGE(bufb ^ 16384, kt + 1) }

        const char* Kl = lds + bufb;
        const char* Vl = lds + bufb + 8192;

        // ---- QK^T swapped (scores already in log2 domain via Q scale) ----
        f32x4 st[4][2] = {};
        __builtin_amdgcn_s_setprio(1);
        #pragma unroll
        for (int tt = 0; tt < 4; ++tt) {
            int row = tt * 16 + qi;
            bf16x8 kf0 = *(const bf16x8*)(Kl + row * 128 +
                          ((g * 16) ^ ((row & 7) << 4)));
            bf16x8 kf1 = *(const bf16x8*)(Kl + row * 128 +
                          ((64 + g * 16) ^ ((row & 7) << 4)));
            #pragma unroll
            for (int u = 0; u < 2; ++u) {
                st[tt][u] = MFMA16(kf0, qf[u][0], st[tt][u]);
                st[tt][u] = MFMA16(kf1, qf[u][1], st[tt][u]);
            }
        }
        __builtin_amdgcn_s_setprio(0);

        // ---- softmax (exp2 domain, defer-max THR=8), per q-column ----
        float pmax[2] = {-1e30f, -1e30f};
        #pragma unroll
        for (int tt = 0; tt < 4; ++tt)
            #pragma unroll
            for (int u = 0; u < 2; ++u)
                #pragma unroll
                for (int r = 0; r < 4; ++r)
                    pmax[u] = fmaxf(pmax[u], st[tt][u][r]);

        bf16x8 pf[2][2];
        #pragma unroll
        for (int u = 0; u < 2; ++u) {
            if (!__all(pmax[u] <= m2[u] + 8.0f)) {
                float gm = fmaxf(pmax[u], __shfl_xor(pmax[u], 16));
                gm = fmaxf(gm, __shfl_xor(gm, 32));
                float newm = fmaxf(m2[u], gm);
                float alpha = EXP2F(m2[u] - newm);
                #pragma unroll
                for (int dt = 0; dt < 4; ++dt)
                    #pragma unroll
                    for (int r = 0; r < 4; ++r) O[dt][u][r] *= alpha;
                lsum[u] *= alpha;
                m2[u] = newm;
            }
#if PERMLANE_P
            unsigned pa[4], pb[4];
            #pragma unroll
            for (int tt = 0; tt < 4; ++tt) {
                float p0 = EXP2F(st[tt][u][0] - m2[u]);
                float p1 = EXP2F(st[tt][u][1] - m2[u]);
                float p2 = EXP2F(st[tt][u][2] - m2[u]);
                float p3 = EXP2F(st[tt][u][3] - m2[u]);
                lsum[u] += (p0 + p1) + (p2 + p3);
                union { bf16x4 h; u32x2 u2; } cv;
                cv.h[0] = (__bf16)p0; cv.h[1] = (__bf16)p1;
                cv.h[2] = (__bf16)p2; cv.h[3] = (__bf16)p3;
                pa[tt] = cv.u2[0]; pb[tt] = cv.u2[1];
            }
            // 2-stage butterfly: lane g's pf[hh] = P^T[kk=hh*32+g*8+j][qi]
            #pragma unroll
            for (int hh = 0; hh < 2; ++hh) {
                const int lo = 2 * hh, hi = 2 * hh + 1;
                unsigned slotA_A, slotB_A, slotA_B, slotB_B;
                {
                    u32x2 rA = __builtin_amdgcn_permlane32_swap(pa[hi], pa[lo], false, false);
                    u32x2 rB = __builtin_amdgcn_permlane32_swap(pa[lo], pa[hi], false, false);
                    slotA_A = v32B ? rB[0] : rA[1];
                    slotB_A = v32B ? rB[1] : rA[0];
                }
                {
                    u32x2 rA = __builtin_amdgcn_permlane32_swap(pb[hi], pb[lo], false, false);
                    u32x2 rB = __builtin_amdgcn_permlane32_swap(pb[lo], pb[hi], false, false);
                    slotA_B = v32B ? rB[0] : rA[1];
                    slotB_B = v32B ? rB[1] : rA[0];
                }
                unsigned fstA, sndA, fstB, sndB;
                {
                    u32x2 rA = __builtin_amdgcn_permlane16_swap(slotA_A, slotB_A, false, false);
                    u32x2 rB = __builtin_amdgcn_permlane16_swap(slotB_A, slotA_A, false, false);
                    fstA = v16B ? rB[1] : rA[0];
                    sndA = v16B ? rB[0] : rA[1];
                }
                {
                    u32x2 rA = __builtin_amdgcn_permlane16_swap(slotA_B, slotB_B, false, false);
                    u32x2 rB = __builtin_amdgcn_permlane16_swap(slotB_B, slotA_B, false, false);
                    fstB = v16B ? rB[1] : rA[0];
                    sndB = v16B ? rB[0] : rA[1];
                }
                union { u32x4 u4; bf16x8 h8; } pc;
                pc.u4[0] = fstA; pc.u4[1] = fstB;
                pc.u4[2] = sndA; pc.u4[3] = sndB;
                pf[u][hh] = pc.h8;
            }
#else
            #pragma unroll
            for (int tt = 0; tt < 4; ++tt) {
                bf16x4 pk;
                #pragma unroll
                for (int r = 0; r < 4; ++r) {
                    float p = EXP2F(st[tt][u][r] - m2[u]);
                    lsum[u] += p;
                    pk[r] = (__bf16)p;
                }
                *(bf16x4*)(Pl + u * 2048 + qi * 128 +
                           ((tt * 32 + g * 8) ^ ((qi & 7) << 4))) = pk;
            }
#endif
        }

#if !PERMLANE_P
        #pragma unroll
        for (int u = 0; u < 2; ++u)
            #pragma unroll
            for (int hh = 0; hh < 2; ++hh)
                pf[u][hh] = *(const bf16x8*)(Pl + u * 2048 + qi * 128 +
                             ((hh * 64 + g * 16) ^ ((qi & 7) << 4)));
#endif

        // ---- PV: O^T[d][q] += V^T[d][k] P^T[k][q] ----
        __builtin_amdgcn_s_setprio(1);
        #pragma unroll
        for (int dt = 0; dt < 4; ++dt) {
            int d = dt * 16 + qi;
            bf16x8 vf0 = *(const bf16x8*)(Vl + d * 128 + ((g * 16) ^ ((d & 7) << 4)));
            bf16x8 vf1 = *(const bf16x8*)(Vl + d * 128 + ((64 + g * 16) ^ ((d & 7) << 4)));
            #pragma unroll
            for (int u = 0; u < 2; ++u) {
                O[dt][u] = MFMA16(vf0, pf[u][0], O[dt][u]);
                O[dt][u] = MFMA16(vf1, pf[u][1], O[dt][u]);
            }
        }
        __builtin_amdgcn_s_setprio(0);

        __syncthreads();
        bufb ^= 16384;
    }

    // ---- epilogue ----
    #pragma unroll
    for (int u = 0; u < 2; ++u) {
        float ls = lsum[u];
        ls += __shfl_xor(ls, 16);
        ls += __shfl_xor(ls, 32);
        const float inv = __builtin_amdgcn_rcpf(ls);
        unsigned short* orow = Aout +
            ((size_t)b * SS + q0 + w * 32 + u * 16 + qi) * EMB + h * DH;
        #pragma unroll
        for (int dt = 0; dt < 4; ++dt) {
            bf16x4 o;
            #pragma unroll
            for (int r = 0; r < 4; ++r) o[r] = (__bf16)(O[dt][u][r] * inv);
            *(bf16x4*)((__bf16*)orow + dt * 16 + g * 4) = o;
        }
    }
#undef ATTN_STAGE
}

// ---------------------------------------------------------------------------
// GroupNorm: Y bf16 [B][C][S] read ONCE into LDS (32KB/group), stats from
// LDS, normalize from LDS, fp32 out.  One block per (group, batch).
// ---------------------------------------------------------------------------
__global__ __launch_bounds__(256) void gnorm3(
    const __bf16* __restrict__ Yb, const float* __restrict__ gw,
    const float* __restrict__ gb, float* __restrict__ out)
{
    __shared__ __align__(16) __bf16 ybuf[CPG * SS];   // 32 KB
    __shared__ float red[8];
    __shared__ float stats[2];

    const int grp = blockIdx.x;
    const int b   = blockIdx.y;
    const int t   = threadIdx.x;
    const size_t base = ((size_t)b * CC + grp * CPG) * SS;   // 16384 elems
    const __bf16* src = Yb + base;

    float sum = 0.f, sq = 0.f;
    #pragma unroll
    for (int i = 0; i < 8; ++i) {
        int off = i * 2048 + t * 8;
        bf16x8 v = *(const bf16x8*)(src + off);
        *(bf16x8*)(ybuf + off) = v;
        #pragma unroll
        for (int j = 0; j < 8; ++j) {
            float f = (float)v[j];
            sum += f; sq += f * f;
        }
    }
    #pragma unroll
    for (int off = 32; off; off >>= 1) {
        sum += __shfl_down(sum, off);
        sq  += __shfl_down(sq, off);
    }
    const int wid = t >> 6;
    if ((t & 63) == 0) { red[wid] = sum; red[4 + wid] = sq; }
    __syncthreads();
    if (t == 0) {
        float s1 = red[0] + red[1] + red[2] + red[3];
        float s2 = red[4] + red[5] + red[6] + red[7];
        float mean = s1 / (float)(CPG * SS);
        float var  = s2 / (float)(CPG * SS) - mean * mean;
        stats[0] = mean;
        stats[1] = rsqrtf(var + EPS);
    }
    __syncthreads();
    const float mean = stats[0], rs = stats[1];

    #pragma unroll
    for (int i = 0; i < 8; ++i) {
        int off = i * 2048 + t * 8;
        int ch = grp * CPG + (off >> 10);
        float wgt = gw[ch] * rs, bet = gb[ch] - mean * rs * gw[ch];
        bf16x8 v = *(const bf16x8*)(ybuf + off);
        float4 o0, o1;
        o0.x = (float)v[0] * wgt + bet; o0.y = (float)v[1] * wgt + bet;
        o0.z = (float)v[2] * wgt + bet; o0.w = (float)v[3] * wgt + bet;
        o1.x = (float)v[4] * wgt + bet; o1.y = (float)v[5] * wgt + bet;
        o1.z = (float)v[6] * wgt + bet; o1.w = (float)v[7] * wgt + bet;
        *(float4*)(out + base + off)     = o0;
        *(float4*)(out + base + off + 4) = o1;
    }
}

// ---------------------------------------------------------------------------
extern "C" void kernel_launch(void* const* d_in, const int* in_sizes, int n_in,
                              void* d_out, int out_size, void* d_ws, size_t ws_size,
                              hipStream_t stream) {
    const float* x   = (const float*)d_in[0];
    const float* Wq  = (const float*)d_in[1];
    const float* bq  = (const float*)d_in[2];
    const float* Wk  = (const float*)d_in[3];
    const float* bk  = (const float*)d_in[4];
    const float* Wv  = (const float*)d_in[5];
    const float* bv  = (const float*)d_in[6];
    const float* Wo  = (const float*)d_in[7];
    const float* bo  = (const float*)d_in[8];
    const float* gnw = (const float*)d_in[9];
    const float* gnb = (const float*)d_in[10];
    float* out = (float*)d_out;
    char* ws  = (char*)d_ws;

    unsigned short* xT  = (unsigned short*)(ws);                       //  8 MB
    unsigned short* Wt  = (unsigned short*)(ws + 8388608);             //  2 MB
    unsigned short* Qb  = (unsigned short*)(ws + 10485760);            //  8 MB
    unsigned short* Kb  = (unsigned short*)(ws + 18874368);            //  8 MB
    unsigned short* Vb  = (unsigned short*)(ws + 27262976);            //  8 MB (V^T)
    unsigned short* AO  = (unsigned short*)(ws + 35651584);            //  8 MB
    unsigned short* Yb  = (unsigned short*)(ws + 44040192);            //  8 MB (bf16)

    prep_all<<<dim3(5120), 256, 0, stream>>>(x, Wq, Wk, Wv, Wo, xT, Wt);
    qkv_mm<<<dim3(64, 4, 3), 256, 0, stream>>>(xT, Wt, bq, bk, bv, Qb, Kb, Vb);
    attn_mfma<<<dim3(512), 256, 0, stream>>>(Qb, Kb, Vb, AO);
    proj_mm<<<dim3(64, 4), 256, 0, stream>>>(AO, Wt + (size_t)3 * EMB * CC, bo, x, Yb);
    gnorm3<<<dim3(32, 8), 256, 0, stream>>>((const __bf16*)Yb, gnw, gnb, out);
}

// Round 10
// 85.340 us; speedup vs baseline: 1.9793x; 1.0334x over previous
//
#include <hip/hip_runtime.h>

#define BB 8
#define CC 512
#define SS 1024   // H*W
#define EMB 512
#define HEADS 8
#define DH 64
#define GROUPS 32
#define CPG 16
#define EPS 1e-5f

typedef __bf16 bf16x8 __attribute__((ext_vector_type(8)));
typedef __bf16 bf16x4 __attribute__((ext_vector_type(4)));
typedef float f32x4 __attribute__((ext_vector_type(4)));
typedef unsigned short u16x4 __attribute__((ext_vector_type(4)));

__device__ inline unsigned short f2bf(float f) {
    union { float f; unsigned u; } c; c.f = f;
    unsigned u = c.u + 0x7FFF + ((c.u >> 16) & 1);   // RNE
    return (unsigned short)(u >> 16);
}

#if defined(__has_builtin)
#if __has_builtin(__builtin_amdgcn_exp2f)
#define EXP2F(x) __builtin_amdgcn_exp2f(x)
#endif
#endif
#ifndef EXP2F
#define EXP2F(x) __expf(0.69314718f * (x))
#endif

#define MFMA16(a, b, c) __builtin_amdgcn_mfma_f32_16x16x32_bf16((a), (b), (c), 0, 0, 0)
#define GLOAD_LDS16(g, s)                                                     \
    __builtin_amdgcn_global_load_lds(                                         \
        (const __attribute__((address_space(1))) void*)(g),                   \
        (__attribute__((address_space(3))) void*)(s), 16, 0, 0)

// ---------------------------------------------------------------------------
// Prep (fused): blocks 0..4095 transpose x -> xT bf16; 4096..5119 transpose
// the four weight matrices -> Wt bf16 (K-major).
// ---------------------------------------------------------------------------
__global__ __launch_bounds__(256) void prep_all(
    const float* __restrict__ x,
    const float* __restrict__ Wq, const float* __restrict__ Wk,
    const float* __restrict__ Wv, const float* __restrict__ Wo,
    unsigned short* __restrict__ xT, unsigned short* __restrict__ Wt)
{
    __shared__ float tile[32][33];
    const int t = threadIdx.x;

    if (blockIdx.x < 4096) {
        const int i  = blockIdx.x;
        const int s0 = (i & 31) * 32;
        const int c0 = ((i >> 5) & 15) * 32;
        const int b  = i >> 9;
        {
            int c = t >> 3, s4 = (t & 7) * 4;
            float4 v = *(const float4*)(x + ((size_t)b * CC + c0 + c) * SS + s0 + s4);
            tile[c][s4] = v.x; tile[c][s4 + 1] = v.y;
            tile[c][s4 + 2] = v.z; tile[c][s4 + 3] = v.w;
        }
        __syncthreads();
        {
            int sr = t >> 3, c4 = (t & 7) * 4;
            u16x4 o;
            #pragma unroll
            for (int i2 = 0; i2 < 4; ++i2) o[i2] = f2bf(tile[c4 + i2][sr]);
            *(u16x4*)(xT + ((size_t)(b << 10) + s0 + sr) * CC + c0 + c4) = o;
        }
    } else {
        const int i  = blockIdx.x - 4096;
        const int k0 = (i & 15) * 32;
        const int n0 = ((i >> 4) & 15) * 32;
        const int z  = i >> 8;
        const float* W = (z == 0) ? Wq : (z == 1) ? Wk : (z == 2) ? Wv : Wo;
        unsigned short* dst = Wt + (size_t)z * EMB * CC;
        {
            int k = t >> 3, n4 = (t & 7) * 4;
            float4 v = *(const float4*)(W + (size_t)(k0 + k) * EMB + n0 + n4);
            tile[k][n4] = v.x; tile[k][n4 + 1] = v.y;
            tile[k][n4 + 2] = v.z; tile[k][n4 + 3] = v.w;
        }
        __syncthreads();
        {
            int n = t >> 3, k4 = (t & 7) * 4;
            u16x4 o;
            #pragma unroll
            for (int i2 = 0; i2 < 4; ++i2) o[i2] = f2bf(tile[k4 + i2][n]);
            *(u16x4*)(dst + (size_t)(n0 + n) * CC + k0 + k4) = o;
        }
    }
}

// ---------------------------------------------------------------------------
// MFMA GEMM core: 128x128 tile, BK=32, 4 waves 2x2, dbuf LDS via
// global_load_lds(16B), slot-XOR swizzle (pre-swizzled source).
// ---------------------------------------------------------------------------
#define GEMM_CORE(Aptr, Bptr)                                                  \
    __shared__ __align__(16) char lds[32768];                                  \
    const int t = threadIdx.x, w = t >> 6, l = t & 63;                         \
    const int wr = w >> 1, wc = w & 1;                                         \
    const int rl = l & 15, kh = l >> 4;                                        \
    f32x4 acc[4][4] = {};                                                      \
    {                                                                          \
        const int srow = w * 32 + (l >> 2);                                    \
        const int sslot = (l & 3) ^ ((srow >> 1) & 3);                         \
        const char* Ag0 = (const char*)(Aptr) + (size_t)(m0 + srow) * 1024 + sslot * 16;      \
        const char* Ag1 = (const char*)(Aptr) + (size_t)(m0 + srow + 16) * 1024 + (((l & 3) ^ (((srow + 16) >> 1) & 3)) * 16); \
        const char* Bg0 = (const char*)(Bptr) + (size_t)(n0 + srow) * 1024 + sslot * 16;      \
        const char* Bg1 = (const char*)(Bptr) + (size_t)(n0 + srow + 16) * 1024 + (((l & 3) ^ (((srow + 16) >> 1) & 3)) * 16); \
        for (int kt = 0; kt < 16; ++kt) {                                      \
            if (kt == 0) {                                                     \
                GLOAD_LDS16(Ag0, lds + w * 2048);                              \
                GLOAD_LDS16(Ag1, lds + w * 2048 + 1024);                       \
                GLOAD_LDS16(Bg0, lds + 8192 + w * 2048);                       \
                GLOAD_LDS16(Bg1, lds + 8192 + w * 2048 + 1024);                \
                __syncthreads();                                               \
            }                                                                  \
            const int buf = kt & 1;                                            \
            if (kt < 15) {                                                     \
                const int kb = (kt + 1) * 64;                                  \
                char* Al = lds + (buf ^ 1) * 16384;                            \
                char* Bl = Al + 8192;                                          \
                GLOAD_LDS16(Ag0 + kb, Al + w * 2048);                          \
                GLOAD_LDS16(Ag1 + kb, Al + w * 2048 + 1024);                   \
                GLOAD_LDS16(Bg0 + kb, Bl + w * 2048);                          \
                GLOAD_LDS16(Bg1 + kb, Bl + w * 2048 + 1024);                   \
            }                                                                  \
            const char* Al = lds + buf * 16384;                                \
            const char* Bl = Al + 8192;                                        \
            bf16x8 af[4], bfr[4];                                              \
            _Pragma("unroll")                                                  \
            for (int i = 0; i < 4; ++i) {                                      \
                int row = wr * 64 + i * 16 + rl;                               \
                af[i] = *(const bf16x8*)(Al + row * 64 + ((kh ^ ((row >> 1) & 3)) << 4)); \
                int col = wc * 64 + i * 16 + rl;                               \
                bfr[i] = *(const bf16x8*)(Bl + col * 64 + ((kh ^ ((col >> 1) & 3)) << 4)); \
            }                                                                  \
            _Pragma("unroll")                                                  \
            for (int i = 0; i < 4; ++i)                                        \
                _Pragma("unroll")                                              \
                for (int j = 0; j < 4; ++j)                                    \
                    acc[i][j] = MFMA16(af[i], bfr[j], acc[i][j]);              \
            __syncthreads();                                                   \
        }                                                                      \
    }

// QKV: A = xT, B = Wt[z].  Q scaled by DH^-0.5*log2(e) (softmax scale
// folded in).  Q/K bf16 [B][H][S][DH]; V bf16 transposed [B][H][DH][S].
__global__ __launch_bounds__(256) void qkv_mm(
    const unsigned short* __restrict__ xT, const unsigned short* __restrict__ Wt,
    const float* __restrict__ bq, const float* __restrict__ bk,
    const float* __restrict__ bv,
    unsigned short* __restrict__ Qb, unsigned short* __restrict__ Kb,
    unsigned short* __restrict__ Vb)
{
    const int z = blockIdx.z;
    const unsigned short* Bt = Wt + (size_t)z * EMB * CC;
    const float* bias = (z == 0) ? bq : (z == 1) ? bk : bv;
    const int m0 = blockIdx.x * 128, n0 = blockIdx.y * 128;

    GEMM_CORE(xT, Bt)

    if (z == 2) {
        #pragma unroll
        for (int i = 0; i < 4; ++i) {
            #pragma unroll
            for (int j = 0; j < 4; ++j) {
                int n = n0 + wc * 64 + j * 16 + rl;
                int h = n >> 6, d = n & 63;
                float bi = bias[n];
                int mb = m0 + wr * 64 + i * 16 + kh * 4;
                int b = mb >> 10, s = mb & 1023;
                bf16x4 o;
                #pragma unroll
                for (int r = 0; r < 4; ++r) o[r] = (__bf16)(acc[i][j][r] + bi);
                *(bf16x4*)((__bf16*)Vb + (((size_t)(b * HEADS + h)) * DH + d) * SS + s) = o;
            }
        }
    } else {
        unsigned short* outp = (z == 0) ? Qb : Kb;
        const float qs = (z == 0) ? 0.1803368801f : 1.0f;   // 0.125*log2(e)
        #pragma unroll
        for (int i = 0; i < 4; ++i) {
            #pragma unroll
            for (int j = 0; j < 4; ++j) {
                int n = n0 + wc * 64 + j * 16 + rl;
                int h = n >> 6, d = n & 63;
                float bi = bias[n];
                #pragma unroll
                for (int r = 0; r < 4; ++r) {
                    int m = m0 + wr * 64 + i * 16 + kh * 4 + r;
                    int b = m >> 10, s = m & 1023;
                    ((__bf16*)outp)[(((size_t)(b * HEADS + h)) * SS + s) * DH + d] =
                        (__bf16)((acc[i][j][r] + bi) * qs);
                }
            }
        }
    }
}

// proj: A = AO bf16, B = Wot; out Y bf16 [B][C][S] = acc + bo + residual.
__global__ __launch_bounds__(256) void proj_mm(
    const unsigned short* __restrict__ AO, const unsigned short* __restrict__ Wot,
    const float* __restrict__ bo, const float* __restrict__ x,
    unsigned short* __restrict__ Yb)
{
    const int m0 = blockIdx.x * 128, n0 = blockIdx.y * 128;

    GEMM_CORE(AO, Wot)

    #pragma unroll
    for (int i = 0; i < 4; ++i) {
        #pragma unroll
        for (int j = 0; j < 4; ++j) {
            int n = n0 + wc * 64 + j * 16 + rl;
            float bi = bo[n];
            int mb = m0 + wr * 64 + i * 16 + kh * 4;
            int b = mb >> 10, s = mb & 1023;
            const float4 xr = *(const float4*)(x + ((size_t)b * CC + n) * SS + s);
            bf16x4 o;
            o[0] = (__bf16)(acc[i][j][0] + bi + xr.x);
            o[1] = (__bf16)(acc[i][j][1] + bi + xr.y);
            o[2] = (__bf16)(acc[i][j][2] + bi + xr.z);
            o[3] = (__bf16)(acc[i][j][3] + bi + xr.w);
            *(bf16x4*)((__bf16*)Yb + ((size_t)b * CC + n) * SS + s) = o;
        }
    }
}

// ---------------------------------------------------------------------------
// MFMA flash attention v7: R6 data path (KVBLK=64, 32 q/wave, K + V^T staged
// via global_load_lds dbuf with pre-swizzled source, LDS P round-trip,
// defer-max softmax in exp2 domain, setprio, XCD remap) but with 2-WAVE
// blocks of 64 q-rows: grid 1024 -> 4 independent barrier domains per CU
// (was 2), overlapping each block's per-tile vmcnt/barrier drain with the
// other blocks' compute.  LDS: K/V dbuf 32KB + 2x4KB P = 40KB (4 blocks/CU).
// ---------------------------------------------------------------------------
__global__ __launch_bounds__(128) void attn_mfma(
    const unsigned short* __restrict__ Q, const unsigned short* __restrict__ K,
    const unsigned short* __restrict__ V, unsigned short* __restrict__ Aout)
{
    __shared__ __align__(16) char lds[40960];

    // XCD-aware remap: 16 q-blocks of one (b,h) stay on one XCD.
    const int wg  = blockIdx.x;          // 0..1023
    const int xcd = wg & 7;
    const int idx = wg >> 3;             // 0..127
    const int pair = xcd * 8 + (idx >> 4);   // 0..63
    const int qb   = idx & 15;
    const int h = pair & 7;
    const int b = pair >> 3;
    const int q0 = qb * 64;

    const size_t kbase = ((size_t)b * HEADS + h) * SS * DH;   // Q,K layout
    const size_t vbase = ((size_t)b * HEADS + h) * DH * SS;   // V^T layout

    const int t  = threadIdx.x;          // 0..127
    const int w  = t >> 6;               // 0..1
    const int l  = t & 63;
    const int g  = l >> 4;
    const int qi = l & 15;
    char* Pl = lds + 32768 + w * 4096;

    // Q fragments resident in registers: 2 q-columns (u) x 2 k-halves
    bf16x8 qf[2][2];
    #pragma unroll
    for (int u = 0; u < 2; ++u) {
        const unsigned short* qrow =
            Q + kbase + (size_t)(q0 + w * 32 + u * 16 + qi) * DH;
        qf[u][0] = *(const bf16x8*)(qrow + g * 8);
        qf[u][1] = *(const bf16x8*)(qrow + 32 + g * 8);
    }

    // staging addresses (pre-swizzled source, linear LDS dest); 128 threads,
    // each instr covers 16 rows (2KB).
    const int srow = t >> 3;             // 0..15
    const int seg  = t & 7;
    const unsigned short* kg0 = K + kbase + (size_t)srow * DH + ((seg ^ (srow & 7)) * 8);
    const unsigned short* vg0 = V + vbase + (size_t)srow * SS + ((seg ^ (srow & 7)) * 8);

#define ATTN_STAGE(bb, ktn)                                                    \
    GLOAD_LDS16(kg0 + ((ktn) * 64 +  0) * DH, lds + (bb) +         t * 16);    \
    GLOAD_LDS16(kg0 + ((ktn) * 64 + 16) * DH, lds + (bb) + 2048 +  t * 16);    \
    GLOAD_LDS16(kg0 + ((ktn) * 64 + 32) * DH, lds + (bb) + 4096 +  t * 16);    \
    GLOAD_LDS16(kg0 + ((ktn) * 64 + 48) * DH, lds + (bb) + 6144 +  t * 16);    \
    GLOAD_LDS16(vg0 + (ktn) * 64 +  0 * SS,   lds + (bb) + 8192 +  t * 16);    \
    GLOAD_LDS16(vg0 + (ktn) * 64 + 16 * SS,   lds + (bb) + 10240 + t * 16);    \
    GLOAD_LDS16(vg0 + (ktn) * 64 + 32 * SS,   lds + (bb) + 12288 + t * 16);    \
    GLOAD_LDS16(vg0 + (ktn) * 64 + 48 * SS,   lds + (bb) + 14336 + t * 16);

    f32x4 O[4][2] = {};
    float m2[2]   = {-1e30f, -1e30f};
    float lsum[2] = {0.f, 0.f};

    int bufb = 0;
    ATTN_STAGE(0, 0)
    __syncthreads();

    for (int kt = 0; kt < 16; ++kt) {
        if (kt < 15) { ATTN_STAGE(bufb ^ 16384, kt + 1) }

        const char* Kl = lds + bufb;
        const char* Vl = lds + bufb + 8192;

        // ---- QK^T swapped (scores already in log2 domain via Q scale) ----
        f32x4 st[4][2] = {};
        __builtin_amdgcn_s_setprio(1);
        #pragma unroll
        for (int tt = 0; tt < 4; ++tt) {
            int row = tt * 16 + qi;
            bf16x8 kf0 = *(const bf16x8*)(Kl + row * 128 +
                          ((g * 16) ^ ((row & 7) << 4)));
            bf16x8 kf1 = *(const bf16x8*)(Kl + row * 128 +
                          ((64 + g * 16) ^ ((row & 7) << 4)));
            #pragma unroll
            for (int u = 0; u < 2; ++u) {
                st[tt][u] = MFMA16(kf0, qf[u][0], st[tt][u]);
                st[tt][u] = MFMA16(kf1, qf[u][1], st[tt][u]);
            }
        }
        __builtin_amdgcn_s_setprio(0);

        // ---- softmax (exp2 domain, defer-max THR=8), per q-column ----
        float pmax[2] = {-1e30f, -1e30f};
        #pragma unroll
        for (int tt = 0; tt < 4; ++tt)
            #pragma unroll
            for (int u = 0; u < 2; ++u)
                #pragma unroll
                for (int r = 0; r < 4; ++r)
                    pmax[u] = fmaxf(pmax[u], st[tt][u][r]);
        #pragma unroll
        for (int u = 0; u < 2; ++u) {
            if (!__all(pmax[u] <= m2[u] + 8.0f)) {
                float gm = fmaxf(pmax[u], __shfl_xor(pmax[u], 16));
                gm = fmaxf(gm, __shfl_xor(gm, 32));
                float newm = fmaxf(m2[u], gm);
                float alpha = EXP2F(m2[u] - newm);
                #pragma unroll
                for (int dt = 0; dt < 4; ++dt)
                    #pragma unroll
                    for (int r = 0; r < 4; ++r) O[dt][u][r] *= alpha;
                lsum[u] *= alpha;
                m2[u] = newm;
            }
            #pragma unroll
            for (int tt = 0; tt < 4; ++tt) {
                bf16x4 pk;
                #pragma unroll
                for (int r = 0; r < 4; ++r) {
                    float p = EXP2F(st[tt][u][r] - m2[u]);
                    lsum[u] += p;
                    pk[r] = (__bf16)p;
                }
                *(bf16x4*)(Pl + u * 2048 + qi * 128 +
                           ((tt * 32 + g * 8) ^ ((qi & 7) << 4))) = pk;
            }
        }

        // ---- PV: O^T[d][q] += V^T[d][k] P^T[k][q] ----
        bf16x8 pf[2][2];
        #pragma unroll
        for (int u = 0; u < 2; ++u)
            #pragma unroll
            for (int hh = 0; hh < 2; ++hh)
                pf[u][hh] = *(const bf16x8*)(Pl + u * 2048 + qi * 128 +
                             ((hh * 64 + g * 16) ^ ((qi & 7) << 4)));
        __builtin_amdgcn_s_setprio(1);
        #pragma unroll
        for (int dt = 0; dt < 4; ++dt) {
            int d = dt * 16 + qi;
            bf16x8 vf0 = *(const bf16x8*)(Vl + d * 128 + ((g * 16) ^ ((d & 7) << 4)));
            bf16x8 vf1 = *(const bf16x8*)(Vl + d * 128 + ((64 + g * 16) ^ ((d & 7) << 4)));
            #pragma unroll
            for (int u = 0; u < 2; ++u) {
                O[dt][u] = MFMA16(vf0, pf[u][0], O[dt][u]);
                O[dt][u] = MFMA16(vf1, pf[u][1], O[dt][u]);
            }
        }
        __builtin_amdgcn_s_setprio(0);

        __syncthreads();
        bufb ^= 16384;
    }

    // ---- epilogue ----
    #pragma unroll
    for (int u = 0; u < 2; ++u) {
        float ls = lsum[u];
        ls += __shfl_xor(ls, 16);
        ls += __shfl_xor(ls, 32);
        const float inv = __builtin_amdgcn_rcpf(ls);
        unsigned short* orow = Aout +
            ((size_t)b * SS + q0 + w * 32 + u * 16 + qi) * EMB + h * DH;
        #pragma unroll
        for (int dt = 0; dt < 4; ++dt) {
            bf16x4 o;
            #pragma unroll
            for (int r = 0; r < 4; ++r) o[r] = (__bf16)(O[dt][u][r] * inv);
            *(bf16x4*)((__bf16*)orow + dt * 16 + g * 4) = o;
        }
    }
#undef ATTN_STAGE
}

// ---------------------------------------------------------------------------
// GroupNorm: Y bf16 [B][C][S] read ONCE into LDS (32KB/group), stats from
// LDS, normalize from LDS, fp32 out.  One block per (group, batch).
// ---------------------------------------------------------------------------
__global__ __launch_bounds__(256) void gnorm3(
    const __bf16* __restrict__ Yb, const float* __restrict__ gw,
    const float* __restrict__ gb, float* __restrict__ out)
{
    __shared__ __align__(16) __bf16 ybuf[CPG * SS];   // 32 KB
    __shared__ float red[8];
    __shared__ float stats[2];

    const int grp = blockIdx.x;
    const int b   = blockIdx.y;
    const int t   = threadIdx.x;
    const size_t base = ((size_t)b * CC + grp * CPG) * SS;   // 16384 elems
    const __bf16* src = Yb + base;

    float sum = 0.f, sq = 0.f;
    #pragma unroll
    for (int i = 0; i < 8; ++i) {
        int off = i * 2048 + t * 8;
        bf16x8 v = *(const bf16x8*)(src + off);
        *(bf16x8*)(ybuf + off) = v;
        #pragma unroll
        for (int j = 0; j < 8; ++j) {
            float f = (float)v[j];
            sum += f; sq += f * f;
        }
    }
    #pragma unroll
    for (int off = 32; off; off >>= 1) {
        sum += __shfl_down(sum, off);
        sq  += __shfl_down(sq, off);
    }
    const int wid = t >> 6;
    if ((t & 63) == 0) { red[wid] = sum; red[4 + wid] = sq; }
    __syncthreads();
    if (t == 0) {
        float s1 = red[0] + red[1] + red[2] + red[3];
        float s2 = red[4] + red[5] + red[6] + red[7];
        float mean = s1 / (float)(CPG * SS);
        float var  = s2 / (float)(CPG * SS) - mean * mean;
        stats[0] = mean;
        stats[1] = rsqrtf(var + EPS);
    }
    __syncthreads();
    const float mean = stats[0], rs = stats[1];

    #pragma unroll
    for (int i = 0; i < 8; ++i) {
        int off = i * 2048 + t * 8;
        int ch = grp * CPG + (off >> 10);
        float wgt = gw[ch] * rs, bet = gb[ch] - mean * rs * gw[ch];
        bf16x8 v = *(const bf16x8*)(ybuf + off);
        float4 o0, o1;
        o0.x = (float)v[0] * wgt + bet; o0.y = (float)v[1] * wgt + bet;
        o0.z = (float)v[2] * wgt + bet; o0.w = (float)v[3] * wgt + bet;
        o1.x = (float)v[4] * wgt + bet; o1.y = (float)v[5] * wgt + bet;
        o1.z = (float)v[6] * wgt + bet; o1.w = (float)v[7] * wgt + bet;
        *(float4*)(out + base + off)     = o0;
        *(float4*)(out + base + off + 4) = o1;
    }
}

// ---------------------------------------------------------------------------
extern "C" void kernel_launch(void* const* d_in, const int* in_sizes, int n_in,
                              void* d_out, int out_size, void* d_ws, size_t ws_size,
                              hipStream_t stream) {
    const float* x   = (const float*)d_in[0];
    const float* Wq  = (const float*)d_in[1];
    const float* bq  = (const float*)d_in[2];
    const float* Wk  = (const float*)d_in[3];
    const float* bk  = (const float*)d_in[4];
    const float* Wv  = (const float*)d_in[5];
    const float* bv  = (const float*)d_in[6];
    const float* Wo  = (const float*)d_in[7];
    const float* bo  = (const float*)d_in[8];
    const float* gnw = (const float*)d_in[9];
    const float* gnb = (const float*)d_in[10];
    float* out = (float*)d_out;
    char* ws  = (char*)d_ws;

    unsigned short* xT  = (unsigned short*)(ws);                       //  8 MB
    unsigned short* Wt  = (unsigned short*)(ws + 8388608);             //  2 MB
    unsigned short* Qb  = (unsigned short*)(ws + 10485760);            //  8 MB
    unsigned short* Kb  = (unsigned short*)(ws + 18874368);            //  8 MB
    unsigned short* Vb  = (unsigned short*)(ws + 27262976);            //  8 MB (V^T)
    unsigned short* AO  = (unsigned short*)(ws + 35651584);            //  8 MB
    unsigned short* Yb  = (unsigned short*)(ws + 44040192);            //  8 MB (bf16)

    prep_all<<<dim3(5120), 256, 0, stream>>>(x, Wq, Wk, Wv, Wo, xT, Wt);
    qkv_mm<<<dim3(64, 4, 3), 256, 0, stream>>>(xT, Wt, bq, bk, bv, Qb, Kb, Vb);
    attn_mfma<<<dim3(1024), 128, 0, stream>>>(Qb, Kb, Vb, AO);
    proj_mm<<<dim3(64, 4), 256, 0, stream>>>(AO, Wt + (size_t)3 * EMB * CC, bo, x, Yb);
    gnorm3<<<dim3(32, 8), 256, 0, stream>>>((const __bf16*)Yb, gnw, gnb, out);
}

// Round 11
// 85.127 us; speedup vs baseline: 1.9843x; 1.0025x over previous
//
#include <hip/hip_runtime.h>

#define BB 8
#define CC 512
#define SS 1024   // H*W
#define EMB 512
#define HEADS 8
#define DH 64
#define GROUPS 32
#define CPG 16
#define EPS 1e-5f

typedef __bf16 bf16x8 __attribute__((ext_vector_type(8)));
typedef __bf16 bf16x4 __attribute__((ext_vector_type(4)));
typedef float f32x4 __attribute__((ext_vector_type(4)));
typedef unsigned short u16x4 __attribute__((ext_vector_type(4)));

__device__ inline unsigned short f2bf(float f) {
    union { float f; unsigned u; } c; c.f = f;
    unsigned u = c.u + 0x7FFF + ((c.u >> 16) & 1);   // RNE
    return (unsigned short)(u >> 16);
}

#if defined(__has_builtin)
#if __has_builtin(__builtin_amdgcn_exp2f)
#define EXP2F(x) __builtin_amdgcn_exp2f(x)
#endif
#endif
#ifndef EXP2F
#define EXP2F(x) __expf(0.69314718f * (x))
#endif

#define MFMA16(a, b, c) __builtin_amdgcn_mfma_f32_16x16x32_bf16((a), (b), (c), 0, 0, 0)
#define GLOAD_LDS16(g, s)                                                     \
    __builtin_amdgcn_global_load_lds(                                         \
        (const __attribute__((address_space(1))) void*)(g),                   \
        (__attribute__((address_space(3))) void*)(s), 16, 0, 0)

// ---------------------------------------------------------------------------
// Prep (fused): blocks 0..4095 transpose x -> xT bf16; 4096..5119 transpose
// the four weight matrices -> Wt bf16 (K-major).
// ---------------------------------------------------------------------------
__global__ __launch_bounds__(256) void prep_all(
    const float* __restrict__ x,
    const float* __restrict__ Wq, const float* __restrict__ Wk,
    const float* __restrict__ Wv, const float* __restrict__ Wo,
    unsigned short* __restrict__ xT, unsigned short* __restrict__ Wt)
{
    __shared__ float tile[32][33];
    const int t = threadIdx.x;

    if (blockIdx.x < 4096) {
        const int i  = blockIdx.x;
        const int s0 = (i & 31) * 32;
        const int c0 = ((i >> 5) & 15) * 32;
        const int b  = i >> 9;
        {
            int c = t >> 3, s4 = (t & 7) * 4;
            float4 v = *(const float4*)(x + ((size_t)b * CC + c0 + c) * SS + s0 + s4);
            tile[c][s4] = v.x; tile[c][s4 + 1] = v.y;
            tile[c][s4 + 2] = v.z; tile[c][s4 + 3] = v.w;
        }
        __syncthreads();
        {
            int sr = t >> 3, c4 = (t & 7) * 4;
            u16x4 o;
            #pragma unroll
            for (int i2 = 0; i2 < 4; ++i2) o[i2] = f2bf(tile[c4 + i2][sr]);
            *(u16x4*)(xT + ((size_t)(b << 10) + s0 + sr) * CC + c0 + c4) = o;
        }
    } else {
        const int i  = blockIdx.x - 4096;
        const int k0 = (i & 15) * 32;
        const int n0 = ((i >> 4) & 15) * 32;
        const int z  = i >> 8;
        const float* W = (z == 0) ? Wq : (z == 1) ? Wk : (z == 2) ? Wv : Wo;
        unsigned short* dst = Wt + (size_t)z * EMB * CC;
        {
            int k = t >> 3, n4 = (t & 7) * 4;
            float4 v = *(const float4*)(W + (size_t)(k0 + k) * EMB + n0 + n4);
            tile[k][n4] = v.x; tile[k][n4 + 1] = v.y;
            tile[k][n4 + 2] = v.z; tile[k][n4 + 3] = v.w;
        }
        __syncthreads();
        {
            int n = t >> 3, k4 = (t & 7) * 4;
            u16x4 o;
            #pragma unroll
            for (int i2 = 0; i2 < 4; ++i2) o[i2] = f2bf(tile[k4 + i2][n]);
            *(u16x4*)(dst + (size_t)(n0 + n) * CC + k0 + k4) = o;
        }
    }
}

// ---------------------------------------------------------------------------
// MFMA GEMM core: 128x128 tile, BK=32, 4 waves 2x2, dbuf LDS via
// global_load_lds(16B), slot-XOR swizzle (pre-swizzled source).
// ---------------------------------------------------------------------------
#define GEMM_CORE(Aptr, Bptr)                                                  \
    __shared__ __align__(16) char lds[32768];                                  \
    const int t = threadIdx.x, w = t >> 6, l = t & 63;                         \
    const int wr = w >> 1, wc = w & 1;                                         \
    const int rl = l & 15, kh = l >> 4;                                        \
    f32x4 acc[4][4] = {};                                                      \
    {                                                                          \
        const int srow = w * 32 + (l >> 2);                                    \
        const int sslot = (l & 3) ^ ((srow >> 1) & 3);                         \
        const char* Ag0 = (const char*)(Aptr) + (size_t)(m0 + srow) * 1024 + sslot * 16;      \
        const char* Ag1 = (const char*)(Aptr) + (size_t)(m0 + srow + 16) * 1024 + (((l & 3) ^ (((srow + 16) >> 1) & 3)) * 16); \
        const char* Bg0 = (const char*)(Bptr) + (size_t)(n0 + srow) * 1024 + sslot * 16;      \
        const char* Bg1 = (const char*)(Bptr) + (size_t)(n0 + srow + 16) * 1024 + (((l & 3) ^ (((srow + 16) >> 1) & 3)) * 16); \
        for (int kt = 0; kt < 16; ++kt) {                                      \
            if (kt == 0) {                                                     \
                GLOAD_LDS16(Ag0, lds + w * 2048);                              \
                GLOAD_LDS16(Ag1, lds + w * 2048 + 1024);                       \
                GLOAD_LDS16(Bg0, lds + 8192 + w * 2048);                       \
                GLOAD_LDS16(Bg1, lds + 8192 + w * 2048 + 1024);                \
                __syncthreads();                                               \
            }                                                                  \
            const int buf = kt & 1;                                            \
            if (kt < 15) {                                                     \
                const int kb = (kt + 1) * 64;                                  \
                char* Al = lds + (buf ^ 1) * 16384;                            \
                char* Bl = Al + 8192;                                          \
                GLOAD_LDS16(Ag0 + kb, Al + w * 2048);                          \
                GLOAD_LDS16(Ag1 + kb, Al + w * 2048 + 1024);                   \
                GLOAD_LDS16(Bg0 + kb, Bl + w * 2048);                          \
                GLOAD_LDS16(Bg1 + kb, Bl + w * 2048 + 1024);                   \
            }                                                                  \
            const char* Al = lds + buf * 16384;                                \
            const char* Bl = Al + 8192;                                        \
            bf16x8 af[4], bfr[4];                                              \
            _Pragma("unroll")                                                  \
            for (int i = 0; i < 4; ++i) {                                      \
                int row = wr * 64 + i * 16 + rl;                               \
                af[i] = *(const bf16x8*)(Al + row * 64 + ((kh ^ ((row >> 1) & 3)) << 4)); \
                int col = wc * 64 + i * 16 + rl;                               \
                bfr[i] = *(const bf16x8*)(Bl + col * 64 + ((kh ^ ((col >> 1) & 3)) << 4)); \
            }                                                                  \
            _Pragma("unroll")                                                  \
            for (int i = 0; i < 4; ++i)                                        \
                _Pragma("unroll")                                              \
                for (int j = 0; j < 4; ++j)                                    \
                    acc[i][j] = MFMA16(af[i], bfr[j], acc[i][j]);              \
            __syncthreads();                                                   \
        }                                                                      \
    }

// QKV: A = xT, B = Wt[z].  Q scaled by DH^-0.5*log2(e) (softmax scale
// folded in).  Q/K bf16 [B][H][S][DH]; V bf16 transposed [B][H][DH][S].
__global__ __launch_bounds__(256) void qkv_mm(
    const unsigned short* __restrict__ xT, const unsigned short* __restrict__ Wt,
    const float* __restrict__ bq, const float* __restrict__ bk,
    const float* __restrict__ bv,
    unsigned short* __restrict__ Qb, unsigned short* __restrict__ Kb,
    unsigned short* __restrict__ Vb)
{
    const int z = blockIdx.z;
    const unsigned short* Bt = Wt + (size_t)z * EMB * CC;
    const float* bias = (z == 0) ? bq : (z == 1) ? bk : bv;
    const int m0 = blockIdx.x * 128, n0 = blockIdx.y * 128;

    GEMM_CORE(xT, Bt)

    if (z == 2) {
        #pragma unroll
        for (int i = 0; i < 4; ++i) {
            #pragma unroll
            for (int j = 0; j < 4; ++j) {
                int n = n0 + wc * 64 + j * 16 + rl;
                int h = n >> 6, d = n & 63;
                float bi = bias[n];
                int mb = m0 + wr * 64 + i * 16 + kh * 4;
                int b = mb >> 10, s = mb & 1023;
                bf16x4 o;
                #pragma unroll
                for (int r = 0; r < 4; ++r) o[r] = (__bf16)(acc[i][j][r] + bi);
                *(bf16x4*)((__bf16*)Vb + (((size_t)(b * HEADS + h)) * DH + d) * SS + s) = o;
            }
        }
    } else {
        unsigned short* outp = (z == 0) ? Qb : Kb;
        const float qs = (z == 0) ? 0.1803368801f : 1.0f;   // 0.125*log2(e)
        #pragma unroll
        for (int i = 0; i < 4; ++i) {
            #pragma unroll
            for (int j = 0; j < 4; ++j) {
                int n = n0 + wc * 64 + j * 16 + rl;
                int h = n >> 6, d = n & 63;
                float bi = bias[n];
                #pragma unroll
                for (int r = 0; r < 4; ++r) {
                    int m = m0 + wr * 64 + i * 16 + kh * 4 + r;
                    int b = m >> 10, s = m & 1023;
                    ((__bf16*)outp)[(((size_t)(b * HEADS + h)) * SS + s) * DH + d] =
                        (__bf16)((acc[i][j][r] + bi) * qs);
                }
            }
        }
    }
}

// proj: A = AO bf16, B = Wot; out Y bf16 [B][C][S] = acc + bo + residual.
__global__ __launch_bounds__(256) void proj_mm(
    const unsigned short* __restrict__ AO, const unsigned short* __restrict__ Wot,
    const float* __restrict__ bo, const float* __restrict__ x,
    unsigned short* __restrict__ Yb)
{
    const int m0 = blockIdx.x * 128, n0 = blockIdx.y * 128;

    GEMM_CORE(AO, Wot)

    #pragma unroll
    for (int i = 0; i < 4; ++i) {
        #pragma unroll
        for (int j = 0; j < 4; ++j) {
            int n = n0 + wc * 64 + j * 16 + rl;
            float bi = bo[n];
            int mb = m0 + wr * 64 + i * 16 + kh * 4;
            int b = mb >> 10, s = mb & 1023;
            const float4 xr = *(const float4*)(x + ((size_t)b * CC + n) * SS + s);
            bf16x4 o;
            o[0] = (__bf16)(acc[i][j][0] + bi + xr.x);
            o[1] = (__bf16)(acc[i][j][1] + bi + xr.y);
            o[2] = (__bf16)(acc[i][j][2] + bi + xr.z);
            o[3] = (__bf16)(acc[i][j][3] + bi + xr.w);
            *(bf16x4*)((__bf16*)Yb + ((size_t)b * CC + n) * SS + s) = o;
        }
    }
}

// ---------------------------------------------------------------------------
// MFMA flash attention v8: R10 structure (KVBLK=64, 2 waves x 32 q-rows,
// K + V^T staged via global_load_lds dbuf, pre-swizzled source, LDS P
// round-trip, defer-max softmax, setprio, XCD remap) with T4 counted-vmcnt:
// raw s_barrier + s_waitcnt vmcnt(8) — the 8 prefetch loads for tile t+1
// stay IN FLIGHT across the barrier instead of being drained to 0 every
// tile (__syncthreads semantics).  vmcnt(0) only on the last tile.
// Hazards: cross-wave staged-data visibility = own vmcnt(8) + barrier;
// WAR on dbuf = trailing barrier (readers of the stage target finished
// one tile ago); ds_reads all consumed by MFMAs pre-barrier (compiler
// lgkmcnt).  sched_barrier(0) fences per rule #18.
// ---------------------------------------------------------------------------
__global__ __launch_bounds__(128) void attn_mfma(
    const unsigned short* __restrict__ Q, const unsigned short* __restrict__ K,
    const unsigned short* __restrict__ V, unsigned short* __restrict__ Aout)
{
    __shared__ __align__(16) char lds[40960];

    // XCD-aware remap: 16 q-blocks of one (b,h) stay on one XCD.
    const int wg  = blockIdx.x;          // 0..1023
    const int xcd = wg & 7;
    const int idx = wg >> 3;             // 0..127
    const int pair = xcd * 8 + (idx >> 4);   // 0..63
    const int qb   = idx & 15;
    const int h = pair & 7;
    const int b = pair >> 3;
    const int q0 = qb * 64;

    const size_t kbase = ((size_t)b * HEADS + h) * SS * DH;   // Q,K layout
    const size_t vbase = ((size_t)b * HEADS + h) * DH * SS;   // V^T layout

    const int t  = threadIdx.x;          // 0..127
    const int w  = t >> 6;               // 0..1
    const int l  = t & 63;
    const int g  = l >> 4;
    const int qi = l & 15;
    char* Pl = lds + 32768 + w * 4096;

    // Q fragments resident in registers: 2 q-columns (u) x 2 k-halves
    bf16x8 qf[2][2];
    #pragma unroll
    for (int u = 0; u < 2; ++u) {
        const unsigned short* qrow =
            Q + kbase + (size_t)(q0 + w * 32 + u * 16 + qi) * DH;
        qf[u][0] = *(const bf16x8*)(qrow + g * 8);
        qf[u][1] = *(const bf16x8*)(qrow + 32 + g * 8);
    }

    // staging addresses (pre-swizzled source, linear LDS dest); 128 threads,
    // each instr covers 16 rows (2KB).
    const int srow = t >> 3;             // 0..15
    const int seg  = t & 7;
    const unsigned short* kg0 = K + kbase + (size_t)srow * DH + ((seg ^ (srow & 7)) * 8);
    const unsigned short* vg0 = V + vbase + (size_t)srow * SS + ((seg ^ (srow & 7)) * 8);

#define ATTN_STAGE(bb, ktn)                                                    \
    GLOAD_LDS16(kg0 + ((ktn) * 64 +  0) * DH, lds + (bb) +         t * 16);    \
    GLOAD_LDS16(kg0 + ((ktn) * 64 + 16) * DH, lds + (bb) + 2048 +  t * 16);    \
    GLOAD_LDS16(kg0 + ((ktn) * 64 + 32) * DH, lds + (bb) + 4096 +  t * 16);    \
    GLOAD_LDS16(kg0 + ((ktn) * 64 + 48) * DH, lds + (bb) + 6144 +  t * 16);    \
    GLOAD_LDS16(vg0 + (ktn) * 64 +  0 * SS,   lds + (bb) + 8192 +  t * 16);    \
    GLOAD_LDS16(vg0 + (ktn) * 64 + 16 * SS,   lds + (bb) + 10240 + t * 16);    \
    GLOAD_LDS16(vg0 + (ktn) * 64 + 32 * SS,   lds + (bb) + 12288 + t * 16);    \
    GLOAD_LDS16(vg0 + (ktn) * 64 + 48 * SS,   lds + (bb) + 14336 + t * 16);

    f32x4 O[4][2] = {};
    float m2[2]   = {-1e30f, -1e30f};
    float lsum[2] = {0.f, 0.f};

    int bufb = 0;
    ATTN_STAGE(0, 0)

    for (int kt = 0; kt < 16; ++kt) {
        // ---- counted-vmcnt pipeline: issue next tile, wait only for ours ----
        if (kt < 15) {
            ATTN_STAGE(bufb ^ 16384, kt + 1)
            asm volatile("s_waitcnt vmcnt(8)" ::: "memory");
        } else {
            asm volatile("s_waitcnt vmcnt(0)" ::: "memory");
        }
        __builtin_amdgcn_sched_barrier(0);
        __builtin_amdgcn_s_barrier();      // all waves' tile-kt stages landed
        __builtin_amdgcn_sched_barrier(0);

        const char* Kl = lds + bufb;
        const char* Vl = lds + bufb + 8192;

        // ---- QK^T swapped (scores already in log2 domain via Q scale) ----
        f32x4 st[4][2] = {};
        __builtin_amdgcn_s_setprio(1);
        #pragma unroll
        for (int tt = 0; tt < 4; ++tt) {
            int row = tt * 16 + qi;
            bf16x8 kf0 = *(const bf16x8*)(Kl + row * 128 +
                          ((g * 16) ^ ((row & 7) << 4)));
            bf16x8 kf1 = *(const bf16x8*)(Kl + row * 128 +
                          ((64 + g * 16) ^ ((row & 7) << 4)));
            #pragma unroll
            for (int u = 0; u < 2; ++u) {
                st[tt][u] = MFMA16(kf0, qf[u][0], st[tt][u]);
                st[tt][u] = MFMA16(kf1, qf[u][1], st[tt][u]);
            }
        }
        __builtin_amdgcn_s_setprio(0);

        // ---- softmax (exp2 domain, defer-max THR=8), per q-column ----
        float pmax[2] = {-1e30f, -1e30f};
        #pragma unroll
        for (int tt = 0; tt < 4; ++tt)
            #pragma unroll
            for (int u = 0; u < 2; ++u)
                #pragma unroll
                for (int r = 0; r < 4; ++r)
                    pmax[u] = fmaxf(pmax[u], st[tt][u][r]);
        #pragma unroll
        for (int u = 0; u < 2; ++u) {
            if (!__all(pmax[u] <= m2[u] + 8.0f)) {
                float gm = fmaxf(pmax[u], __shfl_xor(pmax[u], 16));
                gm = fmaxf(gm, __shfl_xor(gm, 32));
                float newm = fmaxf(m2[u], gm);
                float alpha = EXP2F(m2[u] - newm);
                #pragma unroll
                for (int dt = 0; dt < 4; ++dt)
                    #pragma unroll
                    for (int r = 0; r < 4; ++r) O[dt][u][r] *= alpha;
                lsum[u] *= alpha;
                m2[u] = newm;
            }
            #pragma unroll
            for (int tt = 0; tt < 4; ++tt) {
                bf16x4 pk;
                #pragma unroll
                for (int r = 0; r < 4; ++r) {
                    float p = EXP2F(st[tt][u][r] - m2[u]);
                    lsum[u] += p;
                    pk[r] = (__bf16)p;
                }
                *(bf16x4*)(Pl + u * 2048 + qi * 128 +
                           ((tt * 32 + g * 8) ^ ((qi & 7) << 4))) = pk;
            }
        }

        // ---- PV: O^T[d][q] += V^T[d][k] P^T[k][q] ----
        bf16x8 pf[2][2];
        #pragma unroll
        for (int u = 0; u < 2; ++u)
            #pragma unroll
            for (int hh = 0; hh < 2; ++hh)
                pf[u][hh] = *(const bf16x8*)(Pl + u * 2048 + qi * 128 +
                             ((hh * 64 + g * 16) ^ ((qi & 7) << 4)));
        __builtin_amdgcn_s_setprio(1);
        #pragma unroll
        for (int dt = 0; dt < 4; ++dt) {
            int d = dt * 16 + qi;
            bf16x8 vf0 = *(const bf16x8*)(Vl + d * 128 + ((g * 16) ^ ((d & 7) << 4)));
            bf16x8 vf1 = *(const bf16x8*)(Vl + d * 128 + ((64 + g * 16) ^ ((d & 7) << 4)));
            #pragma unroll
            for (int u = 0; u < 2; ++u) {
                O[dt][u] = MFMA16(vf0, pf[u][0], O[dt][u]);
                O[dt][u] = MFMA16(vf1, pf[u][1], O[dt][u]);
            }
        }
        __builtin_amdgcn_s_setprio(0);

        __builtin_amdgcn_sched_barrier(0);
        __builtin_amdgcn_s_barrier();      // readers of this buf done -> next
        __builtin_amdgcn_sched_barrier(0); // iteration may overwrite it
        bufb ^= 16384;
    }

    // ---- epilogue ----
    #pragma unroll
    for (int u = 0; u < 2; ++u) {
        float ls = lsum[u];
        ls += __shfl_xor(ls, 16);
        ls += __shfl_xor(ls, 32);
        const float inv = __builtin_amdgcn_rcpf(ls);
        unsigned short* orow = Aout +
            ((size_t)b * SS + q0 + w * 32 + u * 16 + qi) * EMB + h * DH;
        #pragma unroll
        for (int dt = 0; dt < 4; ++dt) {
            bf16x4 o;
            #pragma unroll
            for (int r = 0; r < 4; ++r) o[r] = (__bf16)(O[dt][u][r] * inv);
            *(bf16x4*)((__bf16*)orow + dt * 16 + g * 4) = o;
        }
    }
#undef ATTN_STAGE
}

// ---------------------------------------------------------------------------
// GroupNorm: Y bf16 [B][C][S] read ONCE into LDS (32KB/group), stats from
// LDS, normalize from LDS, fp32 out.  One block per (group, batch).
// ---------------------------------------------------------------------------
__global__ __launch_bounds__(256) void gnorm3(
    const __bf16* __restrict__ Yb, const float* __restrict__ gw,
    const float* __restrict__ gb, float* __restrict__ out)
{
    __shared__ __align__(16) __bf16 ybuf[CPG * SS];   // 32 KB
    __shared__ float red[8];
    __shared__ float stats[2];

    const int grp = blockIdx.x;
    const int b   = blockIdx.y;
    const int t   = threadIdx.x;
    const size_t base = ((size_t)b * CC + grp * CPG) * SS;   // 16384 elems
    const __bf16* src = Yb + base;

    float sum = 0.f, sq = 0.f;
    #pragma unroll
    for (int i = 0; i < 8; ++i) {
        int off = i * 2048 + t * 8;
        bf16x8 v = *(const bf16x8*)(src + off);
        *(bf16x8*)(ybuf + off) = v;
        #pragma unroll
        for (int j = 0; j < 8; ++j) {
            float f = (float)v[j];
            sum += f; sq += f * f;
        }
    }
    #pragma unroll
    for (int off = 32; off; off >>= 1) {
        sum += __shfl_down(sum, off);
        sq  += __shfl_down(sq, off);
    }
    const int wid = t >> 6;
    if ((t & 63) == 0) { red[wid] = sum; red[4 + wid] = sq; }
    __syncthreads();
    if (t == 0) {
        float s1 = red[0] + red[1] + red[2] + red[3];
        float s2 = red[4] + red[5] + red[6] + red[7];
        float mean = s1 / (float)(CPG * SS);
        float var  = s2 / (float)(CPG * SS) - mean * mean;
        stats[0] = mean;
        stats[1] = rsqrtf(var + EPS);
    }
    __syncthreads();
    const float mean = stats[0], rs = stats[1];

    #pragma unroll
    for (int i = 0; i < 8; ++i) {
        int off = i * 2048 + t * 8;
        int ch = grp * CPG + (off >> 10);
        float wgt = gw[ch] * rs, bet = gb[ch] - mean * rs * gw[ch];
        bf16x8 v = *(const bf16x8*)(ybuf + off);
        float4 o0, o1;
        o0.x = (float)v[0] * wgt + bet; o0.y = (float)v[1] * wgt + bet;
        o0.z = (float)v[2] * wgt + bet; o0.w = (float)v[3] * wgt + bet;
        o1.x = (float)v[4] * wgt + bet; o1.y = (float)v[5] * wgt + bet;
        o1.z = (float)v[6] * wgt + bet; o1.w = (float)v[7] * wgt + bet;
        *(float4*)(out + base + off)     = o0;
        *(float4*)(out + base + off + 4) = o1;
    }
}

// ---------------------------------------------------------------------------
extern "C" void kernel_launch(void* const* d_in, const int* in_sizes, int n_in,
                              void* d_out, int out_size, void* d_ws, size_t ws_size,
                              hipStream_t stream) {
    const float* x   = (const float*)d_in[0];
    const float* Wq  = (const float*)d_in[1];
    const float* bq  = (const float*)d_in[2];
    const float* Wk  = (const float*)d_in[3];
    const float* bk  = (const float*)d_in[4];
    const float* Wv  = (const float*)d_in[5];
    const float* bv  = (const float*)d_in[6];
    const float* Wo  = (const float*)d_in[7];
    const float* bo  = (const float*)d_in[8];
    const float* gnw = (const float*)d_in[9];
    const float* gnb = (const float*)d_in[10];
    float* out = (float*)d_out;
    char* ws  = (char*)d_ws;

    unsigned short* xT  = (unsigned short*)(ws);                       //  8 MB
    unsigned short* Wt  = (unsigned short*)(ws + 8388608);             //  2 MB
    unsigned short* Qb  = (unsigned short*)(ws + 10485760);            //  8 MB
    unsigned short* Kb  = (unsigned short*)(ws + 18874368);            //  8 MB
    unsigned short* Vb  = (unsigned short*)(ws + 27262976);            //  8 MB (V^T)
    unsigned short* AO  = (unsigned short*)(ws + 35651584);            //  8 MB
    unsigned short* Yb  = (unsigned short*)(ws + 44040192);            //  8 MB (bf16)

    prep_all<<<dim3(5120), 256, 0, stream>>>(x, Wq, Wk, Wv, Wo, xT, Wt);
    qkv_mm<<<dim3(64, 4, 3), 256, 0, stream>>>(xT, Wt, bq, bk, bv, Qb, Kb, Vb);
    attn_mfma<<<dim3(1024), 128, 0, stream>>>(Qb, Kb, Vb, AO);
    proj_mm<<<dim3(64, 4), 256, 0, stream>>>(AO, Wt + (size_t)3 * EMB * CC, bo, x, Yb);
    gnorm3<<<dim3(32, 8), 256, 0, stream>>>((const __bf16*)Yb, gnw, gnb, out);
}

// Round 12
// 84.357 us; speedup vs baseline: 2.0024x; 1.0091x over previous
//
#include <hip/hip_runtime.h>

#define BB 8
#define CC 512
#define SS 1024   // H*W
#define EMB 512
#define HEADS 8
#define DH 64
#define GROUPS 32
#define CPG 16
#define EPS 1e-5f

typedef __bf16 bf16x8 __attribute__((ext_vector_type(8)));
typedef __bf16 bf16x4 __attribute__((ext_vector_type(4)));
typedef float f32x4 __attribute__((ext_vector_type(4)));
typedef unsigned short u16x4 __attribute__((ext_vector_type(4)));

__device__ inline unsigned short f2bf(float f) {
    union { float f; unsigned u; } c; c.f = f;
    unsigned u = c.u + 0x7FFF + ((c.u >> 16) & 1);   // RNE
    return (unsigned short)(u >> 16);
}

#if defined(__has_builtin)
#if __has_builtin(__builtin_amdgcn_exp2f)
#define EXP2F(x) __builtin_amdgcn_exp2f(x)
#endif
#endif
#ifndef EXP2F
#define EXP2F(x) __expf(0.69314718f * (x))
#endif

#define MFMA16(a, b, c) __builtin_amdgcn_mfma_f32_16x16x32_bf16((a), (b), (c), 0, 0, 0)
#define GLOAD_LDS16(g, s)                                                     \
    __builtin_amdgcn_global_load_lds(                                         \
        (const __attribute__((address_space(1))) void*)(g),                   \
        (__attribute__((address_space(3))) void*)(s), 16, 0, 0)

// ---------------------------------------------------------------------------
// Prep (fused): blocks 0..4095 transpose x -> xT bf16; 4096..5119 transpose
// the four weight matrices -> Wt bf16 (K-major).
// ---------------------------------------------------------------------------
__global__ __launch_bounds__(256) void prep_all(
    const float* __restrict__ x,
    const float* __restrict__ Wq, const float* __restrict__ Wk,
    const float* __restrict__ Wv, const float* __restrict__ Wo,
    unsigned short* __restrict__ xT, unsigned short* __restrict__ Wt)
{
    __shared__ float tile[32][33];
    const int t = threadIdx.x;

    if (blockIdx.x < 4096) {
        const int i  = blockIdx.x;
        const int s0 = (i & 31) * 32;
        const int c0 = ((i >> 5) & 15) * 32;
        const int b  = i >> 9;
        {
            int c = t >> 3, s4 = (t & 7) * 4;
            float4 v = *(const float4*)(x + ((size_t)b * CC + c0 + c) * SS + s0 + s4);
            tile[c][s4] = v.x; tile[c][s4 + 1] = v.y;
            tile[c][s4 + 2] = v.z; tile[c][s4 + 3] = v.w;
        }
        __syncthreads();
        {
            int sr = t >> 3, c4 = (t & 7) * 4;
            u16x4 o;
            #pragma unroll
            for (int i2 = 0; i2 < 4; ++i2) o[i2] = f2bf(tile[c4 + i2][sr]);
            *(u16x4*)(xT + ((size_t)(b << 10) + s0 + sr) * CC + c0 + c4) = o;
        }
    } else {
        const int i  = blockIdx.x - 4096;
        const int k0 = (i & 15) * 32;
        const int n0 = ((i >> 4) & 15) * 32;
        const int z  = i >> 8;
        const float* W = (z == 0) ? Wq : (z == 1) ? Wk : (z == 2) ? Wv : Wo;
        unsigned short* dst = Wt + (size_t)z * EMB * CC;
        {
            int k = t >> 3, n4 = (t & 7) * 4;
            float4 v = *(const float4*)(W + (size_t)(k0 + k) * EMB + n0 + n4);
            tile[k][n4] = v.x; tile[k][n4 + 1] = v.y;
            tile[k][n4 + 2] = v.z; tile[k][n4 + 3] = v.w;
        }
        __syncthreads();
        {
            int n = t >> 3, k4 = (t & 7) * 4;
            u16x4 o;
            #pragma unroll
            for (int i2 = 0; i2 < 4; ++i2) o[i2] = f2bf(tile[k4 + i2][n]);
            *(u16x4*)(dst + (size_t)(n0 + n) * CC + k0 + k4) = o;
        }
    }
}

// ---------------------------------------------------------------------------
// MFMA GEMM core pieces.  GEMM_IDX defines thread indices; GEMM_LOOP runs
// the 128x128/BK=32 double-buffered loop.  SWP=1 swaps MFMA operands so the
// output is C^T: lane&15 indexes m (row), regs index n (4 consecutive cols)
// -> vectorized [S][DH] stores in the Q/K epilogue.
// ---------------------------------------------------------------------------
#define GEMM_IDX                                                               \
    const int t = threadIdx.x, w = t >> 6, l = t & 63;                         \
    const int wr = w >> 1, wc = w & 1;                                         \
    const int rl = l & 15, kh = l >> 4;

#define GEMM_LOOP(Aptr, Bptr, SWP)                                             \
    {                                                                          \
        const int srow = w * 32 + (l >> 2);                                    \
        const int sslot = (l & 3) ^ ((srow >> 1) & 3);                         \
        const char* Ag0 = (const char*)(Aptr) + (size_t)(m0 + srow) * 1024 + sslot * 16;      \
        const char* Ag1 = (const char*)(Aptr) + (size_t)(m0 + srow + 16) * 1024 + (((l & 3) ^ (((srow + 16) >> 1) & 3)) * 16); \
        const char* Bg0 = (const char*)(Bptr) + (size_t)(n0 + srow) * 1024 + sslot * 16;      \
        const char* Bg1 = (const char*)(Bptr) + (size_t)(n0 + srow + 16) * 1024 + (((l & 3) ^ (((srow + 16) >> 1) & 3)) * 16); \
        for (int kt = 0; kt < 16; ++kt) {                                      \
            if (kt == 0) {                                                     \
                GLOAD_LDS16(Ag0, lds + w * 2048);                              \
                GLOAD_LDS16(Ag1, lds + w * 2048 + 1024);                       \
                GLOAD_LDS16(Bg0, lds + 8192 + w * 2048);                       \
                GLOAD_LDS16(Bg1, lds + 8192 + w * 2048 + 1024);                \
                __syncthreads();                                               \
            }                                                                  \
            const int buf = kt & 1;                                            \
            if (kt < 15) {                                                     \
                const int kb = (kt + 1) * 64;                                  \
                char* Al = lds + (buf ^ 1) * 16384;                            \
                char* Bl = Al + 8192;                                          \
                GLOAD_LDS16(Ag0 + kb, Al + w * 2048);                          \
                GLOAD_LDS16(Ag1 + kb, Al + w * 2048 + 1024);                   \
                GLOAD_LDS16(Bg0 + kb, Bl + w * 2048);                          \
                GLOAD_LDS16(Bg1 + kb, Bl + w * 2048 + 1024);                   \
            }                                                                  \
            const char* Al = lds + buf * 16384;                                \
            const char* Bl = Al + 8192;                                        \
            bf16x8 af[4], bfr[4];                                              \
            _Pragma("unroll")                                                  \
            for (int i = 0; i < 4; ++i) {                                      \
                int row = wr * 64 + i * 16 + rl;                               \
                af[i] = *(const bf16x8*)(Al + row * 64 + ((kh ^ ((row >> 1) & 3)) << 4)); \
                int col = wc * 64 + i * 16 + rl;                               \
                bfr[i] = *(const bf16x8*)(Bl + col * 64 + ((kh ^ ((col >> 1) & 3)) << 4)); \
            }                                                                  \
            _Pragma("unroll")                                                  \
            for (int i = 0; i < 4; ++i)                                        \
                _Pragma("unroll")                                              \
                for (int j = 0; j < 4; ++j)                                    \
                    acc[i][j] = (SWP) ? MFMA16(bfr[j], af[i], acc[i][j])       \
                                      : MFMA16(af[i], bfr[j], acc[i][j]);      \
            __syncthreads();                                                   \
        }                                                                      \
    }

// QKV: A = xT, B = Wt[z].  Q scaled by DH^-0.5*log2(e).  Q/K bf16
// [B][H][S][DH] written via SWAPPED core (vector bf16x4 stores, 4 consecutive
// d);  V bf16 transposed [B][H][DH][S] via normal core (4 consecutive s).
__global__ __launch_bounds__(256) void qkv_mm(
    const unsigned short* __restrict__ xT, const unsigned short* __restrict__ Wt,
    const float* __restrict__ bq, const float* __restrict__ bk,
    const float* __restrict__ bv,
    unsigned short* __restrict__ Qb, unsigned short* __restrict__ Kb,
    unsigned short* __restrict__ Vb)
{
    __shared__ __align__(16) char lds[32768];
    const int z = blockIdx.z;
    const unsigned short* Bt = Wt + (size_t)z * EMB * CC;
    const float* bias = (z == 0) ? bq : (z == 1) ? bk : bv;
    const int m0 = blockIdx.x * 128, n0 = blockIdx.y * 128;
    GEMM_IDX
    f32x4 acc[4][4] = {};

    if (z == 2) {
        GEMM_LOOP(xT, Bt, 0)
        // V^T: [B][H][DH][S], 4 consecutive s -> vector store
        #pragma unroll
        for (int i = 0; i < 4; ++i) {
            #pragma unroll
            for (int j = 0; j < 4; ++j) {
                int n = n0 + wc * 64 + j * 16 + rl;
                int h = n >> 6, d = n & 63;
                float bi = bias[n];
                int mb = m0 + wr * 64 + i * 16 + kh * 4;
                int b = mb >> 10, s = mb & 1023;
                bf16x4 o;
                #pragma unroll
                for (int r = 0; r < 4; ++r) o[r] = (__bf16)(acc[i][j][r] + bi);
                *(bf16x4*)((__bf16*)Vb + (((size_t)(b * HEADS + h)) * DH + d) * SS + s) = o;
            }
        }
    } else {
        GEMM_LOOP(xT, Bt, 1)
        unsigned short* outp = (z == 0) ? Qb : Kb;
        const float qs = (z == 0) ? 0.1803368801f : 1.0f;   // 0.125*log2(e)
        // C^T layout: m = m0+wr*64+i*16+rl (fixed/thread), n = ...+kh*4+r
        #pragma unroll
        for (int i = 0; i < 4; ++i) {
            int m = m0 + wr * 64 + i * 16 + rl;
            int b = m >> 10, s = m & 1023;
            #pragma unroll
            for (int j = 0; j < 4; ++j) {
                int nb = n0 + wc * 64 + j * 16 + kh * 4;
                int h = nb >> 6, d0 = nb & 63;
                float4 bi4 = *(const float4*)(bias + nb);
                bf16x4 o;
                o[0] = (__bf16)((acc[i][j][0] + bi4.x) * qs);
                o[1] = (__bf16)((acc[i][j][1] + bi4.y) * qs);
                o[2] = (__bf16)((acc[i][j][2] + bi4.z) * qs);
                o[3] = (__bf16)((acc[i][j][3] + bi4.w) * qs);
                *(bf16x4*)((__bf16*)outp +
                           (((size_t)(b * HEADS + h)) * SS + s) * DH + d0) = o;
            }
        }
    }
}

// proj: A = AO bf16, B = Wot; out Y bf16 [B][C][S] = acc + bo + residual.
__global__ __launch_bounds__(256) void proj_mm(
    const unsigned short* __restrict__ AO, const unsigned short* __restrict__ Wot,
    const float* __restrict__ bo, const float* __restrict__ x,
    unsigned short* __restrict__ Yb)
{
    __shared__ __align__(16) char lds[32768];
    const int m0 = blockIdx.x * 128, n0 = blockIdx.y * 128;
    GEMM_IDX
    f32x4 acc[4][4] = {};

    GEMM_LOOP(AO, Wot, 0)

    #pragma unroll
    for (int i = 0; i < 4; ++i) {
        #pragma unroll
        for (int j = 0; j < 4; ++j) {
            int n = n0 + wc * 64 + j * 16 + rl;
            float bi = bo[n];
            int mb = m0 + wr * 64 + i * 16 + kh * 4;
            int b = mb >> 10, s = mb & 1023;
            const float4 xr = *(const float4*)(x + ((size_t)b * CC + n) * SS + s);
            bf16x4 o;
            o[0] = (__bf16)(acc[i][j][0] + bi + xr.x);
            o[1] = (__bf16)(acc[i][j][1] + bi + xr.y);
            o[2] = (__bf16)(acc[i][j][2] + bi + xr.z);
            o[3] = (__bf16)(acc[i][j][3] + bi + xr.w);
            *(bf16x4*)((__bf16*)Yb + ((size_t)b * CC + n) * SS + s) = o;
        }
    }
}

// ---------------------------------------------------------------------------
// MFMA flash attention v9 = R6 v3.1 config (KVBLK=64, 4 waves x 32 q-rows,
// grid 512, 48KB LDS, K + V^T via global_load_lds dbuf with pre-swizzled
// source, LDS P round-trip, defer-max softmax in exp2 domain with Q-folded
// scale, setprio, XCD remap) + T4 counted-vmcnt: per tile, s_waitcnt
// vmcnt(4) keeps tile-t+1's 4 stage loads in flight across the single
// leading s_barrier; vmcnt(0) only on the last tile.
// Hazards: RAW = own vmcnt(4)+barrier (oldest 4 = this tile's loads);
// WAR = stage(t+2) issued only after barrier(t+1), which all waves reach
// post-consumption of buf reads from tile t.
// ---------------------------------------------------------------------------
__global__ __launch_bounds__(256) void attn_mfma(
    const unsigned short* __restrict__ Q, const unsigned short* __restrict__ K,
    const unsigned short* __restrict__ V, unsigned short* __restrict__ Aout)
{
    __shared__ __align__(16) char lds[49152];

    // XCD-aware remap: 8 q-blocks of one (b,h) stay on one XCD.
    const int wg  = blockIdx.x;          // 0..511
    const int xcd = wg & 7;
    const int idx = wg >> 3;             // 0..63
    const int pair = xcd * 8 + (idx >> 3);   // 0..63
    const int qb   = idx & 7;
    const int h = pair & 7;
    const int b = pair >> 3;
    const int q0 = qb * 128;

    const size_t kbase = ((size_t)b * HEADS + h) * SS * DH;   // Q,K layout
    const size_t vbase = ((size_t)b * HEADS + h) * DH * SS;   // V^T layout

    const int t  = threadIdx.x;
    const int w  = t >> 6;
    const int l  = t & 63;
    const int g  = l >> 4;
    const int qi = l & 15;
    char* Pl = lds + 32768 + w * 4096;

    // Q fragments resident in registers: 2 q-columns (u) x 2 k-halves
    bf16x8 qf[2][2];
    #pragma unroll
    for (int u = 0; u < 2; ++u) {
        const unsigned short* qrow =
            Q + kbase + (size_t)(q0 + w * 32 + u * 16 + qi) * DH;
        qf[u][0] = *(const bf16x8*)(qrow + g * 8);
        qf[u][1] = *(const bf16x8*)(qrow + 32 + g * 8);
    }

    // staging addresses (pre-swizzled source, linear LDS dest)
    const int srow = t >> 3;             // 0..31
    const int seg  = t & 7;
    const unsigned short* kg0 = K + kbase + (size_t)srow * DH + ((seg ^ (srow & 7)) * 8);
    const unsigned short* vg0 = V + vbase + (size_t)srow * SS + ((seg ^ (srow & 7)) * 8);

#define ATTN_STAGE(bb, ktn)                                                    \
    GLOAD_LDS16(kg0 + (ktn) * 4096, lds + (bb) + t * 16);                      \
    GLOAD_LDS16(kg0 + (ktn) * 4096 + 2048, lds + (bb) + 4096 + t * 16);        \
    GLOAD_LDS16(vg0 + (ktn) * 64, lds + (bb) + 8192 + t * 16);                 \
    GLOAD_LDS16(vg0 + (ktn) * 64 + 32768, lds + (bb) + 12288 + t * 16);

    f32x4 O[4][2] = {};
    float m2[2]   = {-1e30f, -1e30f};
    float lsum[2] = {0.f, 0.f};

    int bufb = 0;
    ATTN_STAGE(0, 0)

    for (int kt = 0; kt < 16; ++kt) {
        if (kt < 15) {
            ATTN_STAGE(bufb ^ 16384, kt + 1)
            asm volatile("s_waitcnt vmcnt(4)" ::: "memory");
        } else {
            asm volatile("s_waitcnt vmcnt(0)" ::: "memory");
        }
        __builtin_amdgcn_sched_barrier(0);
        __builtin_amdgcn_s_barrier();      // all waves' tile-kt stages landed
        __builtin_amdgcn_sched_barrier(0);

        const char* Kl = lds + bufb;
        const char* Vl = lds + bufb + 8192;

        // ---- QK^T swapped (scores already in log2 domain via Q scale) ----
        f32x4 st[4][2] = {};
        __builtin_amdgcn_s_setprio(1);
        #pragma unroll
        for (int tt = 0; tt < 4; ++tt) {
            int row = tt * 16 + qi;
            bf16x8 kf0 = *(const bf16x8*)(Kl + row * 128 +
                          ((g * 16) ^ ((row & 7) << 4)));
            bf16x8 kf1 = *(const bf16x8*)(Kl + row * 128 +
                          ((64 + g * 16) ^ ((row & 7) << 4)));
            #pragma unroll
            for (int u = 0; u < 2; ++u) {
                st[tt][u] = MFMA16(kf0, qf[u][0], st[tt][u]);
                st[tt][u] = MFMA16(kf1, qf[u][1], st[tt][u]);
            }
        }
        __builtin_amdgcn_s_setprio(0);

        // ---- softmax (exp2 domain, defer-max THR=8), per q-column ----
        float pmax[2] = {-1e30f, -1e30f};
        #pragma unroll
        for (int tt = 0; tt < 4; ++tt)
            #pragma unroll
            for (int u = 0; u < 2; ++u)
                #pragma unroll
                for (int r = 0; r < 4; ++r)
                    pmax[u] = fmaxf(pmax[u], st[tt][u][r]);
        #pragma unroll
        for (int u = 0; u < 2; ++u) {
            if (!__all(pmax[u] <= m2[u] + 8.0f)) {
                float gm = fmaxf(pmax[u], __shfl_xor(pmax[u], 16));
                gm = fmaxf(gm, __shfl_xor(gm, 32));
                float newm = fmaxf(m2[u], gm);
                float alpha = EXP2F(m2[u] - newm);
                #pragma unroll
                for (int dt = 0; dt < 4; ++dt)
                    #pragma unroll
                    for (int r = 0; r < 4; ++r) O[dt][u][r] *= alpha;
                lsum[u] *= alpha;
                m2[u] = newm;
            }
            #pragma unroll
            for (int tt = 0; tt < 4; ++tt) {
                bf16x4 pk;
                #pragma unroll
                for (int r = 0; r < 4; ++r) {
                    float p = EXP2F(st[tt][u][r] - m2[u]);
                    lsum[u] += p;
                    pk[r] = (__bf16)p;
                }
                *(bf16x4*)(Pl + u * 2048 + qi * 128 +
                           ((tt * 32 + g * 8) ^ ((qi & 7) << 4))) = pk;
            }
        }

        // ---- PV: O^T[d][q] += V^T[d][k] P^T[k][q] ----
        bf16x8 pf[2][2];
        #pragma unroll
        for (int u = 0; u < 2; ++u)
            #pragma unroll
            for (int hh = 0; hh < 2; ++hh)
                pf[u][hh] = *(const bf16x8*)(Pl + u * 2048 + qi * 128 +
                             ((hh * 64 + g * 16) ^ ((qi & 7) << 4)));
        __builtin_amdgcn_s_setprio(1);
        #pragma unroll
        for (int dt = 0; dt < 4; ++dt) {
            int d = dt * 16 + qi;
            bf16x8 vf0 = *(const bf16x8*)(Vl + d * 128 + ((g * 16) ^ ((d & 7) << 4)));
            bf16x8 vf1 = *(const bf16x8*)(Vl + d * 128 + ((64 + g * 16) ^ ((d & 7) << 4)));
            #pragma unroll
            for (int u = 0; u < 2; ++u) {
                O[dt][u] = MFMA16(vf0, pf[u][0], O[dt][u]);
                O[dt][u] = MFMA16(vf1, pf[u][1], O[dt][u]);
            }
        }
        __builtin_amdgcn_s_setprio(0);

        bufb ^= 16384;
    }

    // ---- epilogue ----
    #pragma unroll
    for (int u = 0; u < 2; ++u) {
        float ls = lsum[u];
        ls += __shfl_xor(ls, 16);
        ls += __shfl_xor(ls, 32);
        const float inv = __builtin_amdgcn_rcpf(ls);
        unsigned short* orow = Aout +
            ((size_t)b * SS + q0 + w * 32 + u * 16 + qi) * EMB + h * DH;
        #pragma unroll
        for (int dt = 0; dt < 4; ++dt) {
            bf16x4 o;
            #pragma unroll
            for (int r = 0; r < 4; ++r) o[r] = (__bf16)(O[dt][u][r] * inv);
            *(bf16x4*)((__bf16*)orow + dt * 16 + g * 4) = o;
        }
    }
#undef ATTN_STAGE
}

// ---------------------------------------------------------------------------
// GroupNorm: Y bf16 [B][C][S] read ONCE into LDS (32KB/group), stats from
// LDS, normalize from LDS, fp32 out.  One block per (group, batch).
// ---------------------------------------------------------------------------
__global__ __launch_bounds__(256) void gnorm3(
    const __bf16* __restrict__ Yb, const float* __restrict__ gw,
    const float* __restrict__ gb, float* __restrict__ out)
{
    __shared__ __align__(16) __bf16 ybuf[CPG * SS];   // 32 KB
    __shared__ float red[8];
    __shared__ float stats[2];

    const int grp = blockIdx.x;
    const int b   = blockIdx.y;
    const int t   = threadIdx.x;
    const size_t base = ((size_t)b * CC + grp * CPG) * SS;   // 16384 elems
    const __bf16* src = Yb + base;

    float sum = 0.f, sq = 0.f;
    #pragma unroll
    for (int i = 0; i < 8; ++i) {
        int off = i * 2048 + t * 8;
        bf16x8 v = *(const bf16x8*)(src + off);
        *(bf16x8*)(ybuf + off) = v;
        #pragma unroll
        for (int j = 0; j < 8; ++j) {
            float f = (float)v[j];
            sum += f; sq += f * f;
        }
    }
    #pragma unroll
    for (int off = 32; off; off >>= 1) {
        sum += __shfl_down(sum, off);
        sq  += __shfl_down(sq, off);
    }
    const int wid = t >> 6;
    if ((t & 63) == 0) { red[wid] = sum; red[4 + wid] = sq; }
    __syncthreads();
    if (t == 0) {
        float s1 = red[0] + red[1] + red[2] + red[3];
        float s2 = red[4] + red[5] + red[6] + red[7];
        float mean = s1 / (float)(CPG * SS);
        float var  = s2 / (float)(CPG * SS) - mean * mean;
        stats[0] = mean;
        stats[1] = rsqrtf(var + EPS);
    }
    __syncthreads();
    const float mean = stats[0], rs = stats[1];

    #pragma unroll
    for (int i = 0; i < 8; ++i) {
        int off = i * 2048 + t * 8;
        int ch = grp * CPG + (off >> 10);
        float wgt = gw[ch] * rs, bet = gb[ch] - mean * rs * gw[ch];
        bf16x8 v = *(const bf16x8*)(ybuf + off);
        float4 o0, o1;
        o0.x = (float)v[0] * wgt + bet; o0.y = (float)v[1] * wgt + bet;
        o0.z = (float)v[2] * wgt + bet; o0.w = (float)v[3] * wgt + bet;
        o1.x = (float)v[4] * wgt + bet; o1.y = (float)v[5] * wgt + bet;
        o1.z = (float)v[6] * wgt + bet; o1.w = (float)v[7] * wgt + bet;
        *(float4*)(out + base + off)     = o0;
        *(float4*)(out + base + off + 4) = o1;
    }
}

// ---------------------------------------------------------------------------
extern "C" void kernel_launch(void* const* d_in, const int* in_sizes, int n_in,
                              void* d_out, int out_size, void* d_ws, size_t ws_size,
                              hipStream_t stream) {
    const float* x   = (const float*)d_in[0];
    const float* Wq  = (const float*)d_in[1];
    const float* bq  = (const float*)d_in[2];
    const float* Wk  = (const float*)d_in[3];
    const float* bk  = (const float*)d_in[4];
    const float* Wv  = (const float*)d_in[5];
    const float* bv  = (const float*)d_in[6];
    const float* Wo  = (const float*)d_in[7];
    const float* bo  = (const float*)d_in[8];
    const float* gnw = (const float*)d_in[9];
    const float* gnb = (const float*)d_in[10];
    float* out = (float*)d_out;
    char* ws  = (char*)d_ws;

    unsigned short* xT  = (unsigned short*)(ws);                       //  8 MB
    unsigned short* Wt  = (unsigned short*)(ws + 8388608);             //  2 MB
    unsigned short* Qb  = (unsigned short*)(ws + 10485760);            //  8 MB
    unsigned short* Kb  = (unsigned short*)(ws + 18874368);            //  8 MB
    unsigned short* Vb  = (unsigned short*)(ws + 27262976);            //  8 MB (V^T)
    unsigned short* AO  = (unsigned short*)(ws + 35651584);            //  8 MB
    unsigned short* Yb  = (unsigned short*)(ws + 44040192);            //  8 MB (bf16)

    prep_all<<<dim3(5120), 256, 0, stream>>>(x, Wq, Wk, Wv, Wo, xT, Wt);
    qkv_mm<<<dim3(64, 4, 3), 256, 0, stream>>>(xT, Wt, bq, bk, bv, Qb, Kb, Vb);
    attn_mfma<<<dim3(512), 256, 0, stream>>>(Qb, Kb, Vb, AO);
    proj_mm<<<dim3(64, 4), 256, 0, stream>>>(AO, Wt + (size_t)3 * EMB * CC, bo, x, Yb);
    gnorm3<<<dim3(32, 8), 256, 0, stream>>>((const __bf16*)Yb, gnw, gnb, out);
}